// Round 3
// baseline (4727.537 us; speedup 1.0000x reference)
//
#include <hip/hip_runtime.h>
#include <hip/hip_bf16.h>

#define DD 128
#define N_NODE 10000
#define N_EDGE 40000
#define N_LAYER 15

enum { SRC_F32 = 0, SRC_NODE_ENC, SRC_EDGE_CONCAT, SRC_NODE_CONCAT };
enum { EPI_STORE = 0, EPI_EDGE_FINAL, EPI_NODE_FINAL };

// C[M,128] = act(A[M,K] @ W[K,128] + bias), fp32 in/compute.
// BM=64, BN=128 (full), BK=32, 256 threads, 8x4 micro-tile per thread.
// A staged TRANSPOSED in LDS (As[k][m]): inner-loop fragment reads are
// contiguous 32B (2x ds_read_b128) and wave-broadcast (conflict-free).
template<int ASRC, bool RELU, int EPI>
__global__ __launch_bounds__(256)
void gemm128(const float* __restrict__ Af, int K, int lda,
             const float* __restrict__ W, const float* __restrict__ bias,
             float* __restrict__ out, float* __restrict__ agg,
             const int* __restrict__ edges,
             const float* __restrict__ Vbuf, const float* __restrict__ Ebuf,
             const float* __restrict__ posf, const float* __restrict__ areaf,
             const float* __restrict__ infof, int M)
{
    __shared__ __align__(16) float As[32][68];   // [k][m], pad 64->68 (16B-align kept)
    __shared__ __align__(16) float Ws[32][128];  // [k][n]

    const int tid  = threadIdx.x;
    const int row0 = blockIdx.x * 64;
    const int cg   = tid & 31;   // cols cg*4 .. cg*4+3
    const int rg   = tid >> 5;   // rows rg*8 .. rg*8+7
    const int lm   = tid & 63;   // loader: row within tile
    const int lkg  = tid >> 6;   // loader: k-octet 0..3
    const int gm   = row0 + lm;

    int si = 0, ri = 0;
    if (ASRC == SRC_EDGE_CONCAT) {
        if (gm < M) { si = edges[2*gm]; ri = edges[2*gm+1]; }
    }

    float acc[8][4];
    #pragma unroll
    for (int i = 0; i < 8; ++i)
        #pragma unroll
        for (int j = 0; j < 4; ++j) acc[i][j] = 0.f;

    for (int k0 = 0; k0 < K; k0 += 32) {
        // ---- stage W tile: 32x128 fp32; full tiles are contiguous -> float4
        if (K - k0 >= 32) {
            const float4* Wt = (const float4*)(W + (size_t)k0 * DD);
            #pragma unroll
            for (int i = 0; i < 4; ++i) {
                int idx = tid + i * 256;          // 1024 float4 total
                int kk = idx >> 5, n4 = idx & 31;
                ((float4*)(&Ws[kk][0]))[n4] = Wt[idx];
            }
        } else {
            #pragma unroll
            for (int i = 0; i < 16; ++i) {
                int l  = tid + i * 256;
                int kk = l >> 7, nn = l & 127;
                int kg = k0 + kk;
                Ws[kk][nn] = (kg < K) ? W[(size_t)kg * DD + nn] : 0.f;
            }
        }
        // ---- stage A tile (transposed), 8 elems/thread; gather/concat fused
        #pragma unroll
        for (int i = 0; i < 8; ++i) {
            int kk = lkg * 8 + i;
            int kg = k0 + kk;
            float v = 0.f;
            if (gm < M && kg < K) {
                if (ASRC == SRC_F32) {
                    v = Af[(size_t)gm * lda + kg];
                } else if (ASRC == SRC_EDGE_CONCAT) {      // [V[s] | V[r] | E], K=384
                    if (kg < DD)          v = Vbuf[si * DD + kg];
                    else if (kg < 2 * DD) v = Vbuf[ri * DD + (kg - DD)];
                    else                  v = Ebuf[(size_t)gm * DD + (kg - 2 * DD)];
                } else if (ASRC == SRC_NODE_CONCAT) {      // [V | agg], K=256
                    v = (kg < DD) ? Vbuf[gm * DD + kg] : Ebuf[gm * DD + (kg - DD)];
                } else {                                   // node encoder input, K=12
                    if (kg < 3)       v = posf[gm * 3 + kg];
                    else if (kg == 3) v = areaf[gm];
                    else if (kg < 12) v = infof[kg - 4];
                }
            }
            As[kk][lm] = v;
        }
        __syncthreads();

        #pragma unroll
        for (int kk = 0; kk < 32; ++kk) {
            float a[8], w[4];
            #pragma unroll
            for (int i = 0; i < 8; ++i) a[i] = As[kk][rg * 8 + i];
            #pragma unroll
            for (int j = 0; j < 4; ++j) w[j] = Ws[kk][cg * 4 + j];
            #pragma unroll
            for (int i = 0; i < 8; ++i)
                #pragma unroll
                for (int j = 0; j < 4; ++j)
                    acc[i][j] = fmaf(a[i], w[j], acc[i][j]);
        }
        __syncthreads();
    }

    float bj[4];
    #pragma unroll
    for (int j = 0; j < 4; ++j) bj[j] = bias[cg * 4 + j];

    #pragma unroll
    for (int i = 0; i < 8; ++i) {
        int m = row0 + rg * 8 + i;
        if (m >= M) continue;
        float v[4];
        #pragma unroll
        for (int j = 0; j < 4; ++j) {
            v[j] = acc[i][j] + bj[j];
            if (RELU) v[j] = fmaxf(v[j], 0.f);
        }
        if (EPI == EPI_STORE) {
            *(float4*)(&out[(size_t)m * DD + cg * 4]) = make_float4(v[0], v[1], v[2], v[3]);
        } else if (EPI == EPI_NODE_FINAL) {            // V += v_emb (in place)
            float4* p = (float4*)(&out[(size_t)m * DD + cg * 4]);
            float4 c = *p;
            c.x += v[0]; c.y += v[1]; c.z += v[2]; c.w += v[3];
            *p = c;
        } else {                                       // E += e_emb ; agg[s] += e_emb
            float4* p = (float4*)(&out[(size_t)m * DD + cg * 4]);
            float4 c = *p;
            c.x += v[0]; c.y += v[1]; c.z += v[2]; c.w += v[3];
            *p = c;
            int sm = edges[2 * m];
            atomicAdd(&agg[sm * DD + cg * 4 + 0], v[0]);
            atomicAdd(&agg[sm * DD + cg * 4 + 1], v[1]);
            atomicAdd(&agg[sm * DD + cg * 4 + 2], v[2]);
            atomicAdd(&agg[sm * DD + cg * 4 + 3], v[3]);
        }
    }
}

// E_raw = [dx, dy, dz, |d|] per edge
__global__ __launch_bounds__(256)
void eraw_kernel(const float* __restrict__ pos, const int* __restrict__ edges,
                 float* __restrict__ Eraw, int Eg)
{
    int e = blockIdx.x * 256 + threadIdx.x;
    if (e >= Eg) return;
    int s = edges[2 * e], r = edges[2 * e + 1];
    float dx = pos[3 * s + 0] - pos[3 * r + 0];
    float dy = pos[3 * s + 1] - pos[3 * r + 1];
    float dz = pos[3 * s + 2] - pos[3 * r + 2];
    float n  = sqrtf(dx * dx + dy * dy + dz * dz);
    *(float4*)(&Eraw[4 * e]) = make_float4(dx, dy, dz, n);
}

// in-place LayerNorm over D=128; one wave per row, 4 rows/block
__global__ __launch_bounds__(256)
void ln_kernel(float* __restrict__ X, const float* __restrict__ g,
               const float* __restrict__ b, int rows)
{
    int row  = blockIdx.x * 4 + (threadIdx.x >> 6);
    int lane = threadIdx.x & 63;
    if (row >= rows) return;
    float x0 = X[row * DD + lane];
    float x1 = X[row * DD + 64 + lane];
    float s = x0 + x1, q = x0 * x0 + x1 * x1;
    #pragma unroll
    for (int off = 32; off; off >>= 1) {
        s += __shfl_xor(s, off);
        q += __shfl_xor(q, off);
    }
    float mu  = s * (1.f / 128.f);
    float var = q * (1.f / 128.f) - mu * mu;
    float inv = rsqrtf(var + 1e-5f);
    X[row * DD + lane]      = (x0 - mu) * inv * g[lane]      + b[lane];
    X[row * DD + 64 + lane] = (x1 - mu) * inv * g[64 + lane] + b[64 + lane];
}

// decoder last layer: out[n] = dot(H[n,:], w[128]) + b, fp32 out
__global__ __launch_bounds__(256)
void dec_final(const float* __restrict__ H, const float* __restrict__ w,
               const float* __restrict__ b, float* __restrict__ out, int rows)
{
    int row  = blockIdx.x * 4 + (threadIdx.x >> 6);
    int lane = threadIdx.x & 63;
    if (row >= rows) return;
    float v = H[row * DD + lane] * w[lane]
            + H[row * DD + 64 + lane] * w[64 + lane];
    #pragma unroll
    for (int off = 32; off; off >>= 1) v += __shfl_xor(v, off);
    if (lane == 0) out[row] = v + b[0];
}

extern "C" void kernel_launch(void* const* d_in, const int* in_sizes, int n_in,
                              void* d_out, int out_size, void* d_ws, size_t ws_size,
                              hipStream_t stream)
{
    (void)in_sizes; (void)n_in; (void)out_size; (void)ws_size;

    const float* pos   = (const float*)d_in[0];
    const float* area  = (const float*)d_in[1];
    const float* info  = (const float*)d_in[2];
    const int*   edges = (const int*)d_in[3];
    const float* fv_w1 = (const float*)d_in[4];
    const float* fv_b1 = (const float*)d_in[5];
    const float* fv_w2 = (const float*)d_in[6];
    const float* fv_b2 = (const float*)d_in[7];
    const float* fv_w3 = (const float*)d_in[8];
    const float* fv_b3 = (const float*)d_in[9];
    const float* fv_g  = (const float*)d_in[10];
    const float* fv_bt = (const float*)d_in[11];
    const float* fe_w1 = (const float*)d_in[12];
    const float* fe_b1 = (const float*)d_in[13];
    const float* fe_w2 = (const float*)d_in[14];
    const float* fe_b2 = (const float*)d_in[15];
    const float* fe_w3 = (const float*)d_in[16];
    const float* fe_b3 = (const float*)d_in[17];
    const float* fe_g  = (const float*)d_in[18];
    const float* fe_bt = (const float*)d_in[19];
    const float* ge_w1 = (const float*)d_in[20];
    const float* ge_b1 = (const float*)d_in[21];
    const float* ge_w2 = (const float*)d_in[22];
    const float* ge_b2 = (const float*)d_in[23];
    const float* ge_w3 = (const float*)d_in[24];
    const float* ge_b3 = (const float*)d_in[25];
    const float* gn_w1 = (const float*)d_in[26];
    const float* gn_b1 = (const float*)d_in[27];
    const float* gn_w2 = (const float*)d_in[28];
    const float* gn_b2 = (const float*)d_in[29];
    const float* gn_w3 = (const float*)d_in[30];
    const float* gn_b3 = (const float*)d_in[31];
    const float* de_w1 = (const float*)d_in[32];
    const float* de_b1 = (const float*)d_in[33];
    const float* de_w2 = (const float*)d_in[34];
    const float* de_b2 = (const float*)d_in[35];
    const float* de_w3 = (const float*)d_in[36];
    const float* de_b3 = (const float*)d_in[37];

    // fp32 workspace layout (~71.7 MB); Eraw aliases hB (dead before hB's first write)
    float* V    = (float*)d_ws;
    float* E    = V   + N_NODE * DD;
    float* hA   = E   + N_EDGE * DD;
    float* hB   = hA  + N_EDGE * DD;
    float* agg  = hB  + N_EDGE * DD;
    float* Eraw = hB;

    const int gbE = N_EDGE / 64;            // 625
    const int gbN = (N_NODE + 63) / 64;     // 157
    dim3 blk(256);

    // ---- edge raw features (into hB region; consumed by edge-encoder GEMM-1)
    eraw_kernel<<<(N_EDGE + 255) / 256, blk, 0, stream>>>(pos, edges, Eraw, N_EDGE);

    // ---- node encoder: [N,12] -> 128 -> 128 -> 128, then LN -> V
    gemm128<SRC_NODE_ENC, true,  EPI_STORE><<<gbN, blk, 0, stream>>>(
        nullptr, 12, 0, fv_w1, fv_b1, V, nullptr, nullptr, nullptr, nullptr,
        pos, area, info, N_NODE);
    gemm128<SRC_F32, true,  EPI_STORE><<<gbN, blk, 0, stream>>>(
        V, 128, 128, fv_w2, fv_b2, agg, nullptr, nullptr, nullptr, nullptr,
        nullptr, nullptr, nullptr, N_NODE);
    gemm128<SRC_F32, false, EPI_STORE><<<gbN, blk, 0, stream>>>(
        agg, 128, 128, fv_w3, fv_b3, V, nullptr, nullptr, nullptr, nullptr,
        nullptr, nullptr, nullptr, N_NODE);
    ln_kernel<<<(N_NODE + 3) / 4, blk, 0, stream>>>(V, fv_g, fv_bt, N_NODE);

    // ---- edge encoder: [E,4] -> 128 -> 128 -> 128, then LN -> E
    gemm128<SRC_F32, true,  EPI_STORE><<<gbE, blk, 0, stream>>>(
        Eraw, 4, 4, fe_w1, fe_b1, hA, nullptr, nullptr, nullptr, nullptr,
        nullptr, nullptr, nullptr, N_EDGE);
    gemm128<SRC_F32, true,  EPI_STORE><<<gbE, blk, 0, stream>>>(
        hA, 128, 128, fe_w2, fe_b2, hB, nullptr, nullptr, nullptr, nullptr,
        nullptr, nullptr, nullptr, N_EDGE);
    gemm128<SRC_F32, false, EPI_STORE><<<gbE, blk, 0, stream>>>(
        hB, 128, 128, fe_w3, fe_b3, E, nullptr, nullptr, nullptr, nullptr,
        nullptr, nullptr, nullptr, N_EDGE);
    ln_kernel<<<(N_EDGE + 3) / 4, blk, 0, stream>>>(E, fe_g, fe_bt, N_EDGE);

    // ---- 15 GNN layers
    for (int l = 0; l < N_LAYER; ++l) {
        const float* w1  = ge_w1 + (size_t)l * 384 * DD;
        const float* b1  = ge_b1 + (size_t)l * DD;
        const float* w2  = ge_w2 + (size_t)l * DD * DD;
        const float* b2  = ge_b2 + (size_t)l * DD;
        const float* w3  = ge_w3 + (size_t)l * DD * DD;
        const float* b3  = ge_b3 + (size_t)l * DD;
        const float* nw1 = gn_w1 + (size_t)l * 256 * DD;
        const float* nb1 = gn_b1 + (size_t)l * DD;
        const float* nw2 = gn_w2 + (size_t)l * DD * DD;
        const float* nb2 = gn_b2 + (size_t)l * DD;
        const float* nw3 = gn_w3 + (size_t)l * DD * DD;
        const float* nb3 = gn_b3 + (size_t)l * DD;

        hipMemsetAsync(agg, 0, (size_t)N_NODE * DD * sizeof(float), stream);

        // edge MLP: e_in = [V[s] | V[r] | E] (K=384)
        gemm128<SRC_EDGE_CONCAT, true,  EPI_STORE><<<gbE, blk, 0, stream>>>(
            nullptr, 384, 0, w1, b1, hA, nullptr, edges, V, E,
            nullptr, nullptr, nullptr, N_EDGE);
        gemm128<SRC_F32, true,  EPI_STORE><<<gbE, blk, 0, stream>>>(
            hA, 128, 128, w2, b2, hB, nullptr, nullptr, nullptr, nullptr,
            nullptr, nullptr, nullptr, N_EDGE);
        // e_emb: E += e_emb (in place) and scatter agg[s] += e_emb
        gemm128<SRC_F32, false, EPI_EDGE_FINAL><<<gbE, blk, 0, stream>>>(
            hB, 128, 128, w3, b3, E, agg, edges, nullptr, nullptr,
            nullptr, nullptr, nullptr, N_EDGE);

        // node MLP: n_in = [V | agg] (K=256)
        gemm128<SRC_NODE_CONCAT, true,  EPI_STORE><<<gbN, blk, 0, stream>>>(
            nullptr, 256, 0, nw1, nb1, hA, nullptr, nullptr, V, agg,
            nullptr, nullptr, nullptr, N_NODE);
        gemm128<SRC_F32, true,  EPI_STORE><<<gbN, blk, 0, stream>>>(
            hA, 128, 128, nw2, nb2, hB, nullptr, nullptr, nullptr, nullptr,
            nullptr, nullptr, nullptr, N_NODE);
        // V += v_emb (in place)
        gemm128<SRC_F32, false, EPI_NODE_FINAL><<<gbN, blk, 0, stream>>>(
            hB, 128, 128, nw3, nb3, V, nullptr, nullptr, nullptr, nullptr,
            nullptr, nullptr, nullptr, N_NODE);
    }

    // ---- decoder: 128 -> 128 -> 128 -> 1 (fp32 out)
    gemm128<SRC_F32, true, EPI_STORE><<<gbN, blk, 0, stream>>>(
        V, 128, 128, de_w1, de_b1, hA, nullptr, nullptr, nullptr, nullptr,
        nullptr, nullptr, nullptr, N_NODE);
    gemm128<SRC_F32, true, EPI_STORE><<<gbN, blk, 0, stream>>>(
        hA, 128, 128, de_w2, de_b2, hB, nullptr, nullptr, nullptr, nullptr,
        nullptr, nullptr, nullptr, N_NODE);
    dec_final<<<(N_NODE + 3) / 4, blk, 0, stream>>>(
        hB, de_w3, de_b3, (float*)d_out, N_NODE);
}

// Round 4
// 2130.128 us; speedup vs baseline: 2.2194x; 2.2194x over previous
//
#include <hip/hip_runtime.h>
#include <hip/hip_bf16.h>

#define DD 128
#define N_NODE 10000
#define N_EDGE 40000
#define N_LAYER 15

typedef unsigned short U16;
typedef __attribute__((ext_vector_type(8))) short short8;
typedef __attribute__((ext_vector_type(4))) float f32x4;

enum { A_BF16 = 0, A_EDGE, A_NODE };
enum { EPI_H = 0, EPI_F, EPI_EDGE, EPI_NODE };

// Wt layout offsets (bf16 elements), [n=128][Kpad] per matrix
#define OFF_FV1 0
#define OFF_FV2 4096
#define OFF_FV3 20480
#define OFF_FE1 36864
#define OFF_FE2 40960
#define OFF_FE3 57344
#define OFF_GE1 73728     /* stride 49152 (Kpad=384) */
#define OFF_GE2 811008    /* stride 16384 */
#define OFF_GE3 1056768
#define OFF_GN1 1302528   /* stride 32768 (Kpad=256) */
#define OFF_GN2 1794048
#define OFF_GN3 2039808
#define OFF_DE1 2285568
#define OFF_DE2 2301952
#define WT_TOTAL 2318336

static __device__ __forceinline__ U16 f2b(float f) {
    union { float f; unsigned u; } x; x.f = f;
    unsigned u = x.u;
    return (U16)((u + 0x7fffu + ((u >> 16) & 1u)) >> 16);
}
static __device__ __forceinline__ float b2f(U16 u) {
    union { unsigned u; float f; } x; x.u = ((unsigned)u) << 16;
    return x.f;
}

// ---------------- weight transpose+cast: W[K][128] f32 -> Wt[n][Kpad] bf16 ----
__global__ __launch_bounds__(256)
void wprep(const float* fv1, const float* fv2, const float* fv3,
           const float* fe1, const float* fe2, const float* fe3,
           const float* ge1, const float* ge2, const float* ge3,
           const float* gn1, const float* gn2, const float* gn3,
           const float* de1, const float* de2, U16* Wt)
{
    int b = blockIdx.x;
    const float* src; U16* dst; int K, Kpad, k0;
    if      (b < 1)   { src = fv1; K = 12;  Kpad = 32;  dst = Wt + OFF_FV1; k0 = b * 32; }
    else if (b < 5)   { src = fv2; K = 128; Kpad = 128; dst = Wt + OFF_FV2; k0 = (b-1)*32; }
    else if (b < 9)   { src = fv3; K = 128; Kpad = 128; dst = Wt + OFF_FV3; k0 = (b-5)*32; }
    else if (b < 10)  { src = fe1; K = 4;   Kpad = 32;  dst = Wt + OFF_FE1; k0 = (b-9)*32; }
    else if (b < 14)  { src = fe2; K = 128; Kpad = 128; dst = Wt + OFF_FE2; k0 = (b-10)*32; }
    else if (b < 18)  { src = fe3; K = 128; Kpad = 128; dst = Wt + OFF_FE3; k0 = (b-14)*32; }
    else if (b < 198) { int r = b-18,  mi = r/12, s = r%12; src = ge1 + (size_t)mi*384*128; K = 384; Kpad = 384; dst = Wt + OFF_GE1 + (size_t)mi*49152; k0 = s*32; }
    else if (b < 258) { int r = b-198, mi = r/4,  s = r%4;  src = ge2 + (size_t)mi*16384;   K = 128; Kpad = 128; dst = Wt + OFF_GE2 + (size_t)mi*16384; k0 = s*32; }
    else if (b < 318) { int r = b-258, mi = r/4,  s = r%4;  src = ge3 + (size_t)mi*16384;   K = 128; Kpad = 128; dst = Wt + OFF_GE3 + (size_t)mi*16384; k0 = s*32; }
    else if (b < 438) { int r = b-318, mi = r/8,  s = r%8;  src = gn1 + (size_t)mi*32768;   K = 256; Kpad = 256; dst = Wt + OFF_GN1 + (size_t)mi*32768; k0 = s*32; }
    else if (b < 498) { int r = b-438, mi = r/4,  s = r%4;  src = gn2 + (size_t)mi*16384;   K = 128; Kpad = 128; dst = Wt + OFF_GN2 + (size_t)mi*16384; k0 = s*32; }
    else if (b < 558) { int r = b-498, mi = r/4,  s = r%4;  src = gn3 + (size_t)mi*16384;   K = 128; Kpad = 128; dst = Wt + OFF_GN3 + (size_t)mi*16384; k0 = s*32; }
    else if (b < 562) { src = de1; K = 128; Kpad = 128; dst = Wt + OFF_DE1; k0 = (b-558)*32; }
    else              { src = de2; K = 128; Kpad = 128; dst = Wt + OFF_DE2; k0 = (b-562)*32; }

    __shared__ float T[32][129];
    #pragma unroll
    for (int i = 0; i < 16; ++i) {
        int l = threadIdx.x + i * 256;
        int kk = l >> 7, n = l & 127;
        int kg = k0 + kk;
        T[kk][n] = (kg < K) ? src[(size_t)kg * 128 + n] : 0.f;
    }
    __syncthreads();
    int n = threadIdx.x >> 1, h = threadIdx.x & 1;
    union { U16 u[16]; int4 v[2]; } o;
    #pragma unroll
    for (int j = 0; j < 16; ++j) o.u[j] = f2b(T[h * 16 + j][n]);
    int4* d = (int4*)(dst + (size_t)n * Kpad + k0 + h * 16);
    d[0] = o.v[0]; d[1] = o.v[1];
}

// ---------------- input builders (K padded to 32, bf16) ----------------------
__global__ __launch_bounds__(256)
void encin_kernel(const float* __restrict__ pos, const float* __restrict__ area,
                  const float* __restrict__ info, U16* __restrict__ out, int n_rows)
{
    int n = blockIdx.x * 256 + threadIdx.x;
    if (n >= n_rows) return;
    union { U16 u[32]; int4 v[4]; } o;
    #pragma unroll
    for (int j = 0; j < 32; ++j) o.u[j] = 0;
    o.u[0] = f2b(pos[3*n+0]); o.u[1] = f2b(pos[3*n+1]); o.u[2] = f2b(pos[3*n+2]);
    o.u[3] = f2b(area[n]);
    #pragma unroll
    for (int j = 0; j < 8; ++j) o.u[4+j] = f2b(info[j]);
    int4* d = (int4*)(out + (size_t)n * 32);
    d[0]=o.v[0]; d[1]=o.v[1]; d[2]=o.v[2]; d[3]=o.v[3];
}

__global__ __launch_bounds__(256)
void eraw_kernel(const float* __restrict__ pos, const int* __restrict__ edges,
                 U16* __restrict__ out, int Eg)
{
    int e = blockIdx.x * 256 + threadIdx.x;
    if (e >= Eg) return;
    int s = edges[2*e], r = edges[2*e+1];
    float dx = pos[3*s+0] - pos[3*r+0];
    float dy = pos[3*s+1] - pos[3*r+1];
    float dz = pos[3*s+2] - pos[3*r+2];
    float nm = sqrtf(dx*dx + dy*dy + dz*dz);
    union { U16 u[32]; int4 v[4]; } o;
    #pragma unroll
    for (int j = 0; j < 32; ++j) o.u[j] = 0;
    o.u[0] = f2b(dx); o.u[1] = f2b(dy); o.u[2] = f2b(dz); o.u[3] = f2b(nm);
    int4* d = (int4*)(out + (size_t)e * 32);
    d[0]=o.v[0]; d[1]=o.v[1]; d[2]=o.v[2]; d[3]=o.v[3];
}

// ---------------- MFMA GEMM: C[M,128] = act(A[M,K] @ W + b) ------------------
// BM=128, BN=128, BK=32; 4 waves 2x2, each 64x64 = 4x4 mfma_f32_16x16x32_bf16
template<int ASRC, bool RELU, int EPI>
__global__ __launch_bounds__(256)
void mgemm(const U16* __restrict__ Af, int lda,
           const U16* __restrict__ Wt, int K,
           const float* __restrict__ bias,
           U16* __restrict__ outh, float* __restrict__ outf,
           float* __restrict__ aggp, const int* __restrict__ edges,
           const U16* __restrict__ Vh, const U16* __restrict__ Eh, int M)
{
    __shared__ U16 As[128][40];   // [m][k], +8 pad keeps 16B align, breaks stride
    __shared__ U16 Bs[128][40];   // [n][k]

    const int tid  = threadIdx.x;
    const int row0 = blockIdx.x * 128;
    const int wave = tid >> 6, lane = tid & 63;
    const int quad = lane >> 4, l16 = lane & 15;
    const int wm = (wave >> 1) * 64, wn = (wave & 1) * 64;
    const int sr = tid >> 1, sh = tid & 1;       // staging: row/col, half
    const int sm = row0 + sr;

    int si = 0, ri = 0;
    if (ASRC == A_EDGE) {
        if (sm < M) { si = edges[2*sm]; ri = edges[2*sm+1]; }
    }

    f32x4 acc[4][4];
    #pragma unroll
    for (int i = 0; i < 4; ++i)
        #pragma unroll
        for (int j = 0; j < 4; ++j) acc[i][j] = (f32x4)0.f;

    for (int k0 = 0; k0 < K; k0 += 32) {
        // ---- stage A tile (bf16 [m][k]): 2 threads/row, 16 elems each
        {
            int4 w0, w1;
            bool valid = (sm < M);
            if (ASRC == A_NODE && k0 >= 128) {       // agg is fp32 -> cvt
                float tf[16];
                if (valid) {
                    const float4* s = (const float4*)(outf /*unused*/, (const float*)nullptr);
                    (void)s;
                    const float4* sp = (const float4*)(aggp + (size_t)sm * 128 + (k0 - 128) + sh * 16);
                    float4 a0 = sp[0], a1 = sp[1], a2 = sp[2], a3 = sp[3];
                    tf[0]=a0.x; tf[1]=a0.y; tf[2]=a0.z; tf[3]=a0.w;
                    tf[4]=a1.x; tf[5]=a1.y; tf[6]=a1.z; tf[7]=a1.w;
                    tf[8]=a2.x; tf[9]=a2.y; tf[10]=a2.z; tf[11]=a2.w;
                    tf[12]=a3.x; tf[13]=a3.y; tf[14]=a3.z; tf[15]=a3.w;
                } else {
                    #pragma unroll
                    for (int j = 0; j < 16; ++j) tf[j] = 0.f;
                }
                union { U16 u[16]; int4 v[2]; } pk;
                #pragma unroll
                for (int j = 0; j < 16; ++j) pk.u[j] = f2b(tf[j]);
                w0 = pk.v[0]; w1 = pk.v[1];
            } else {
                const U16* s;
                if (ASRC == A_BF16)      s = Af + (size_t)sm * lda + k0;
                else if (ASRC == A_EDGE) {
                    if (k0 < 128)        s = Vh + (size_t)si * 128 + k0;
                    else if (k0 < 256)   s = Vh + (size_t)ri * 128 + (k0 - 128);
                    else                 s = Eh + (size_t)sm * 128 + (k0 - 256);
                } else                   s = Vh + (size_t)sm * 128 + k0;   // A_NODE low
                s += sh * 16;
                if (valid) { w0 = ((const int4*)s)[0]; w1 = ((const int4*)s)[1]; }
                else       { w0 = make_int4(0,0,0,0); w1 = make_int4(0,0,0,0); }
            }
            *(int4*)&As[sr][sh*16]     = w0;
            *(int4*)&As[sr][sh*16 + 8] = w1;
        }
        // ---- stage W tile (bf16 [n][k]) from pre-transposed Wt
        {
            const U16* s = Wt + (size_t)sr * K + k0 + sh * 16;
            *(int4*)&Bs[sr][sh*16]     = ((const int4*)s)[0];
            *(int4*)&Bs[sr][sh*16 + 8] = ((const int4*)s)[1];
        }
        __syncthreads();

        short8 a[4], bfr[4];
        #pragma unroll
        for (int mt = 0; mt < 4; ++mt) a[mt]   = *(const short8*)&As[wm + mt*16 + l16][quad*8];
        #pragma unroll
        for (int nt = 0; nt < 4; ++nt) bfr[nt] = *(const short8*)&Bs[wn + nt*16 + l16][quad*8];
        #pragma unroll
        for (int mt = 0; mt < 4; ++mt)
            #pragma unroll
            for (int nt = 0; nt < 4; ++nt)
                acc[mt][nt] = __builtin_amdgcn_mfma_f32_16x16x32_bf16(a[mt], bfr[nt], acc[mt][nt], 0, 0, 0);
        __syncthreads();
    }

    // ---- epilogue: C/D layout col=lane&15, row=quad*4+reg
    #pragma unroll
    for (int nt = 0; nt < 4; ++nt) {
        int c = wn + nt * 16 + l16;
        float bv = bias[c];
        #pragma unroll
        for (int mt = 0; mt < 4; ++mt) {
            #pragma unroll
            for (int rg = 0; rg < 4; ++rg) {
                int mg = row0 + wm + mt * 16 + quad * 4 + rg;
                if (mg >= M) continue;
                float v = acc[mt][nt][rg] + bv;
                if (RELU) v = fmaxf(v, 0.f);
                size_t o = (size_t)mg * 128 + c;
                if (EPI == EPI_H) {
                    outh[o] = f2b(v);
                } else if (EPI == EPI_F) {
                    outf[o] = v;
                } else {
                    float nv = outf[o] + v;       // residual in fp32
                    outf[o] = nv;
                    outh[o] = f2b(nv);            // bf16 mirror for next GEMM
                    if (EPI == EPI_EDGE)
                        atomicAdd(&aggp[(size_t)edges[2*mg] * 128 + c], v);
                }
            }
        }
    }
}

// in-place LayerNorm over D=128 on fp32 master + bf16 mirror
__global__ __launch_bounds__(256)
void ln_kernel(float* __restrict__ X, const float* __restrict__ g,
               const float* __restrict__ b, U16* __restrict__ Xh, int rows)
{
    int row  = blockIdx.x * 4 + (threadIdx.x >> 6);
    int lane = threadIdx.x & 63;
    if (row >= rows) return;
    float x0 = X[row * DD + lane];
    float x1 = X[row * DD + 64 + lane];
    float s = x0 + x1, q = x0 * x0 + x1 * x1;
    #pragma unroll
    for (int off = 32; off; off >>= 1) {
        s += __shfl_xor(s, off);
        q += __shfl_xor(q, off);
    }
    float mu  = s * (1.f / 128.f);
    float var = q * (1.f / 128.f) - mu * mu;
    float inv = rsqrtf(var + 1e-5f);
    float y0 = (x0 - mu) * inv * g[lane]      + b[lane];
    float y1 = (x1 - mu) * inv * g[64 + lane] + b[64 + lane];
    X[row * DD + lane]       = y0;
    X[row * DD + 64 + lane]  = y1;
    Xh[row * DD + lane]      = f2b(y0);
    Xh[row * DD + 64 + lane] = f2b(y1);
}

// decoder last layer: out[n] = dot(H[n,:], w[128]) + b  (H bf16, out fp32)
__global__ __launch_bounds__(256)
void dec_final(const U16* __restrict__ H, const float* __restrict__ w,
               const float* __restrict__ b, float* __restrict__ out, int rows)
{
    int row  = blockIdx.x * 4 + (threadIdx.x >> 6);
    int lane = threadIdx.x & 63;
    if (row >= rows) return;
    float v = b2f(H[row * DD + lane]) * w[lane]
            + b2f(H[row * DD + 64 + lane]) * w[64 + lane];
    #pragma unroll
    for (int off = 32; off; off >>= 1) v += __shfl_xor(v, off);
    if (lane == 0) out[row] = v + b[0];
}

extern "C" void kernel_launch(void* const* d_in, const int* in_sizes, int n_in,
                              void* d_out, int out_size, void* d_ws, size_t ws_size,
                              hipStream_t stream)
{
    (void)in_sizes; (void)n_in; (void)out_size; (void)ws_size;

    const float* pos   = (const float*)d_in[0];
    const float* area  = (const float*)d_in[1];
    const float* info  = (const float*)d_in[2];
    const int*   edges = (const int*)d_in[3];
    const float* fv_w1 = (const float*)d_in[4];
    const float* fv_b1 = (const float*)d_in[5];
    const float* fv_w2 = (const float*)d_in[6];
    const float* fv_b2 = (const float*)d_in[7];
    const float* fv_w3 = (const float*)d_in[8];
    const float* fv_b3 = (const float*)d_in[9];
    const float* fv_g  = (const float*)d_in[10];
    const float* fv_bt = (const float*)d_in[11];
    const float* fe_w1 = (const float*)d_in[12];
    const float* fe_b1 = (const float*)d_in[13];
    const float* fe_w2 = (const float*)d_in[14];
    const float* fe_b2 = (const float*)d_in[15];
    const float* fe_w3 = (const float*)d_in[16];
    const float* fe_b3 = (const float*)d_in[17];
    const float* fe_g  = (const float*)d_in[18];
    const float* fe_bt = (const float*)d_in[19];
    const float* ge_w1 = (const float*)d_in[20];
    const float* ge_b1 = (const float*)d_in[21];
    const float* ge_w2 = (const float*)d_in[22];
    const float* ge_b2 = (const float*)d_in[23];
    const float* ge_w3 = (const float*)d_in[24];
    const float* ge_b3 = (const float*)d_in[25];
    const float* gn_w1 = (const float*)d_in[26];
    const float* gn_b1 = (const float*)d_in[27];
    const float* gn_w2 = (const float*)d_in[28];
    const float* gn_b2 = (const float*)d_in[29];
    const float* gn_w3 = (const float*)d_in[30];
    const float* gn_b3 = (const float*)d_in[31];
    const float* de_w1 = (const float*)d_in[32];
    const float* de_b1 = (const float*)d_in[33];
    const float* de_w2 = (const float*)d_in[34];
    const float* de_b2 = (const float*)d_in[35];
    const float* de_w3 = (const float*)d_in[36];
    const float* de_b3 = (const float*)d_in[37];

    // workspace layout (68.67 MB)
    char* p = (char*)d_ws;
    float* Vf   = (float*)p;  p += (size_t)N_NODE * 128 * 4;
    float* Ef   = (float*)p;  p += (size_t)N_EDGE * 128 * 4;
    float* aggp = (float*)p;  p += (size_t)N_NODE * 128 * 4;
    U16*  Vh    = (U16*)p;    p += (size_t)N_NODE * 128 * 2;
    U16*  Eh    = (U16*)p;    p += (size_t)N_EDGE * 128 * 2;
    U16*  hA    = (U16*)p;    p += (size_t)40064 * 128 * 2;
    U16*  hB    = (U16*)p;    p += (size_t)40064 * 128 * 2;
    U16*  Wt    = (U16*)p;    p += (size_t)WT_TOTAL * 2;
    U16*  enc_in = (U16*)aggp;   // alias: agg unused until layer loop
    U16*  eraw_h = hA;           // alias: dead after edge-enc GEMM1

    const int gbE = (N_EDGE + 127) / 128;   // 313
    const int gbN = (N_NODE + 127) / 128;   // 79
    dim3 blk(256);

    // ---- prep: weights transpose+cast, padded bf16 inputs
    wprep<<<566, blk, 0, stream>>>(fv_w1, fv_w2, fv_w3, fe_w1, fe_w2, fe_w3,
                                   ge_w1, ge_w2, ge_w3, gn_w1, gn_w2, gn_w3,
                                   de_w1, de_w2, Wt);
    encin_kernel<<<(N_NODE + 255) / 256, blk, 0, stream>>>(pos, area, info, enc_in, N_NODE);
    eraw_kernel<<<(N_EDGE + 255) / 256, blk, 0, stream>>>(pos, edges, eraw_h, N_EDGE);

    // ---- edge encoder: eraw(hA) -> hB -> Eh -> E_f32, LN -> Ef + Eh
    mgemm<A_BF16, true,  EPI_H><<<gbE, blk, 0, stream>>>(
        eraw_h, 32, Wt + OFF_FE1, 32, fe_b1, hB, nullptr, nullptr, nullptr, nullptr, nullptr, N_EDGE);
    mgemm<A_BF16, true,  EPI_H><<<gbE, blk, 0, stream>>>(
        hB, 128, Wt + OFF_FE2, 128, fe_b2, Eh, nullptr, nullptr, nullptr, nullptr, nullptr, N_EDGE);
    mgemm<A_BF16, false, EPI_F><<<gbE, blk, 0, stream>>>(
        Eh, 128, Wt + OFF_FE3, 128, fe_b3, nullptr, Ef, nullptr, nullptr, nullptr, nullptr, N_EDGE);
    ln_kernel<<<(N_EDGE + 3) / 4, blk, 0, stream>>>(Ef, fe_g, fe_bt, Eh, N_EDGE);

    // ---- node encoder: enc_in(agg) -> hA -> hB -> V_f32, LN -> Vf + Vh
    mgemm<A_BF16, true,  EPI_H><<<gbN, blk, 0, stream>>>(
        enc_in, 32, Wt + OFF_FV1, 32, fv_b1, hA, nullptr, nullptr, nullptr, nullptr, nullptr, N_NODE);
    mgemm<A_BF16, true,  EPI_H><<<gbN, blk, 0, stream>>>(
        hA, 128, Wt + OFF_FV2, 128, fv_b2, hB, nullptr, nullptr, nullptr, nullptr, nullptr, N_NODE);
    mgemm<A_BF16, false, EPI_F><<<gbN, blk, 0, stream>>>(
        hB, 128, Wt + OFF_FV3, 128, fv_b3, nullptr, Vf, nullptr, nullptr, nullptr, nullptr, N_NODE);
    ln_kernel<<<(N_NODE + 3) / 4, blk, 0, stream>>>(Vf, fv_g, fv_bt, Vh, N_NODE);

    // ---- 15 GNN layers
    for (int l = 0; l < N_LAYER; ++l) {
        hipMemsetAsync(aggp, 0, (size_t)N_NODE * 128 * sizeof(float), stream);

        // edge MLP: [Vh[s] | Vh[r] | Eh] (K=384) -> hA -> hB -> E+=, Eh, agg
        mgemm<A_EDGE, true,  EPI_H><<<gbE, blk, 0, stream>>>(
            nullptr, 0, Wt + OFF_GE1 + (size_t)l * 49152, 384, ge_b1 + (size_t)l * 128,
            hA, nullptr, nullptr, edges, Vh, Eh, N_EDGE);
        mgemm<A_BF16, true,  EPI_H><<<gbE, blk, 0, stream>>>(
            hA, 128, Wt + OFF_GE2 + (size_t)l * 16384, 128, ge_b2 + (size_t)l * 128,
            hB, nullptr, nullptr, nullptr, nullptr, nullptr, N_EDGE);
        mgemm<A_BF16, false, EPI_EDGE><<<gbE, blk, 0, stream>>>(
            hB, 128, Wt + OFF_GE3 + (size_t)l * 16384, 128, ge_b3 + (size_t)l * 128,
            Eh, Ef, aggp, edges, nullptr, nullptr, N_EDGE);

        // node MLP: [Vh | agg] (K=256) -> hA -> hB -> V+=, Vh
        mgemm<A_NODE, true,  EPI_H><<<gbN, blk, 0, stream>>>(
            nullptr, 0, Wt + OFF_GN1 + (size_t)l * 32768, 256, gn_b1 + (size_t)l * 128,
            hA, nullptr, aggp, nullptr, Vh, nullptr, N_NODE);
        mgemm<A_BF16, true,  EPI_H><<<gbN, blk, 0, stream>>>(
            hA, 128, Wt + OFF_GN2 + (size_t)l * 16384, 128, gn_b2 + (size_t)l * 128,
            hB, nullptr, nullptr, nullptr, nullptr, nullptr, N_NODE);
        mgemm<A_BF16, false, EPI_NODE><<<gbN, blk, 0, stream>>>(
            hB, 128, Wt + OFF_GN3 + (size_t)l * 16384, 128, gn_b3 + (size_t)l * 128,
            Vh, Vf, nullptr, nullptr, nullptr, nullptr, N_NODE);
    }

    // ---- decoder: Vh -> hA -> hB -> out (fp32)
    mgemm<A_BF16, true, EPI_H><<<gbN, blk, 0, stream>>>(
        Vh, 128, Wt + OFF_DE1, 128, de_b1, hA, nullptr, nullptr, nullptr, nullptr, nullptr, N_NODE);
    mgemm<A_BF16, true, EPI_H><<<gbN, blk, 0, stream>>>(
        hA, 128, Wt + OFF_DE2, 128, de_b2, hB, nullptr, nullptr, nullptr, nullptr, nullptr, N_NODE);
    dec_final<<<(N_NODE + 3) / 4, blk, 0, stream>>>(
        hB, de_w3, de_b3, (float*)d_out, N_NODE);
}

// Round 5
// 1930.900 us; speedup vs baseline: 2.4484x; 1.1032x over previous
//
#include <hip/hip_runtime.h>

#define DD 128
#define N_NODE 10000
#define N_EDGE 40000
#define N_LAYER 15

typedef unsigned short U16;
typedef __attribute__((ext_vector_type(8))) short short8;
typedef __attribute__((ext_vector_type(4))) float f32x4;

enum { A_BF16 = 0, A_EDGE, A_NODE, A_ENCIN, A_ERAW };
enum { EPI_F = 0, EPI_EDGE, EPI_NODE, EPI_DEC };

// Wt layout offsets (bf16 elements), [n=128][Kpad] per matrix
#define OFF_FV1 0
#define OFF_FV2 4096
#define OFF_FV3 20480
#define OFF_FE1 36864
#define OFF_FE2 40960
#define OFF_FE3 57344
#define OFF_GE1 73728     /* stride 49152 (Kpad=384) */
#define OFF_GE2 811008    /* stride 16384 */
#define OFF_GE3 1056768
#define OFF_GN1 1302528   /* stride 32768 (Kpad=256) */
#define OFF_GN2 1794048
#define OFF_GN3 2039808
#define OFF_DE1 2285568
#define OFF_DE2 2301952
#define WT_TOTAL 2318336

static __device__ __forceinline__ U16 f2b(float f) {
    union { float f; unsigned u; } x; x.f = f;
    unsigned u = x.u;
    return (U16)((u + 0x7fffu + ((u >> 16) & 1u)) >> 16);
}
static __device__ __forceinline__ float b2f(U16 u) {
    union { unsigned u; float f; } x; x.u = ((unsigned)u) << 16;
    return x.f;
}

// ---------------- weight transpose+cast: W[K][128] f32 -> Wt[n][Kpad] bf16 ----
__global__ __launch_bounds__(256)
void wprep(const float* fv1, const float* fv2, const float* fv3,
           const float* fe1, const float* fe2, const float* fe3,
           const float* ge1, const float* ge2, const float* ge3,
           const float* gn1, const float* gn2, const float* gn3,
           const float* de1, const float* de2, U16* Wt)
{
    int b = blockIdx.x;
    const float* src; U16* dst; int K, Kpad, k0;
    if      (b < 1)   { src = fv1; K = 12;  Kpad = 32;  dst = Wt + OFF_FV1; k0 = b * 32; }
    else if (b < 5)   { src = fv2; K = 128; Kpad = 128; dst = Wt + OFF_FV2; k0 = (b-1)*32; }
    else if (b < 9)   { src = fv3; K = 128; Kpad = 128; dst = Wt + OFF_FV3; k0 = (b-5)*32; }
    else if (b < 10)  { src = fe1; K = 4;   Kpad = 32;  dst = Wt + OFF_FE1; k0 = (b-9)*32; }
    else if (b < 14)  { src = fe2; K = 128; Kpad = 128; dst = Wt + OFF_FE2; k0 = (b-10)*32; }
    else if (b < 18)  { src = fe3; K = 128; Kpad = 128; dst = Wt + OFF_FE3; k0 = (b-14)*32; }
    else if (b < 198) { int r = b-18,  mi = r/12, s = r%12; src = ge1 + (size_t)mi*384*128; K = 384; Kpad = 384; dst = Wt + OFF_GE1 + (size_t)mi*49152; k0 = s*32; }
    else if (b < 258) { int r = b-198, mi = r/4,  s = r%4;  src = ge2 + (size_t)mi*16384;   K = 128; Kpad = 128; dst = Wt + OFF_GE2 + (size_t)mi*16384; k0 = s*32; }
    else if (b < 318) { int r = b-258, mi = r/4,  s = r%4;  src = ge3 + (size_t)mi*16384;   K = 128; Kpad = 128; dst = Wt + OFF_GE3 + (size_t)mi*16384; k0 = s*32; }
    else if (b < 438) { int r = b-318, mi = r/8,  s = r%8;  src = gn1 + (size_t)mi*32768;   K = 256; Kpad = 256; dst = Wt + OFF_GN1 + (size_t)mi*32768; k0 = s*32; }
    else if (b < 498) { int r = b-438, mi = r/4,  s = r%4;  src = gn2 + (size_t)mi*16384;   K = 128; Kpad = 128; dst = Wt + OFF_GN2 + (size_t)mi*16384; k0 = s*32; }
    else if (b < 558) { int r = b-498, mi = r/4,  s = r%4;  src = gn3 + (size_t)mi*16384;   K = 128; Kpad = 128; dst = Wt + OFF_GN3 + (size_t)mi*16384; k0 = s*32; }
    else if (b < 562) { src = de1; K = 128; Kpad = 128; dst = Wt + OFF_DE1; k0 = (b-558)*32; }
    else              { src = de2; K = 128; Kpad = 128; dst = Wt + OFF_DE2; k0 = (b-562)*32; }

    __shared__ float T[32][129];
    #pragma unroll
    for (int i = 0; i < 16; ++i) {
        int l = threadIdx.x + i * 256;
        int kk = l >> 7, n = l & 127;
        int kg = k0 + kk;
        T[kk][n] = (kg < K) ? src[(size_t)kg * 128 + n] : 0.f;
    }
    __syncthreads();
    int n = threadIdx.x >> 1, h = threadIdx.x & 1;
    union { U16 u[16]; int4 v[2]; } o;
    #pragma unroll
    for (int j = 0; j < 16; ++j) o.u[j] = f2b(T[h * 16 + j][n]);
    int4* d = (int4*)(dst + (size_t)n * Kpad + k0 + h * 16);
    d[0] = o.v[0]; d[1] = o.v[1];
}

// ---------------- fused 3-layer MLP (MFMA, weights-as-A orientation) ---------
// Computes h^T = W^T · act^T so each lane owns 4 consecutive output columns.
// BM rows/block, BN=128 (full); per-phase LDS round-trip through Hs.
template<int ASRC, int EPI, int BM>
__global__ __launch_bounds__(BM * 2)
void mlp3(const U16* __restrict__ Af, int K1,
          const U16* __restrict__ W1, const float* __restrict__ b1,
          const U16* __restrict__ W2, const float* __restrict__ b2,
          const U16* __restrict__ W3, const float* __restrict__ b3,
          U16* __restrict__ outh, float* __restrict__ outf,
          float* aggp, const int* __restrict__ edges,
          const U16* __restrict__ Vh, const U16* __restrict__ Ehp,
          const float* __restrict__ pos, const float* __restrict__ area,
          const float* __restrict__ info, const float* __restrict__ w3f,
          int M)
{
    __shared__ U16 As[BM][40];     // phase-1 activation tile [m][k]
    __shared__ U16 Bs[128][40];    // weight tile [n][k]
    __shared__ U16 Hs[BM][132];    // inter-phase activations [m][n]

    const int tid  = threadIdx.x;
    const int row0 = blockIdx.x * BM;
    const int wave = tid >> 6, lane = tid & 63;
    const int quad = lane >> 4, l16 = lane & 15;
    const int wm = (wave >> 1) * 64;   // m-offset of this wave (0 for BM=64)
    const int wn = (wave & 1) * 64;    // n-offset of this wave
    const int sr = tid >> 1, sh = tid & 1;     // staging row / 16-elem half
    const int sm = row0 + sr;
    const bool valid = (sm < M);

    int si = 0, ri = 0;
    if ((ASRC == A_EDGE || ASRC == A_ERAW) && valid) {
        si = edges[2 * sm]; ri = edges[2 * sm + 1];
    }

    f32x4 acc[4][4];   // acc[wg][ag][rg]: n = wn+wg*16+quad*4+rg, m = wm+ag*16+l16

    auto zacc = [&] {
        #pragma unroll
        for (int i = 0; i < 4; ++i)
            #pragma unroll
            for (int j = 0; j < 4; ++j) acc[i][j] = (f32x4)0.f;
    };

    auto stage_W = [&](const U16* W, int Kw, int k0) {
        #pragma unroll
        for (int it = 0; it < 128 / BM; ++it) {
            int r = sr + it * BM;
            const U16* s = W + (size_t)r * Kw + k0 + sh * 16;
            *(int4*)&Bs[r][sh * 16]     = ((const int4*)s)[0];
            *(int4*)&Bs[r][sh * 16 + 8] = ((const int4*)s)[1];
        }
    };

    auto stage_A = [&](int k0) {
        union { U16 u[16]; int4 v[2]; } pk;
        if (ASRC == A_ENCIN || ASRC == A_ERAW) {
            #pragma unroll
            for (int j = 0; j < 16; ++j) pk.u[j] = 0;
            if (valid && sh == 0) {
                if (ASRC == A_ENCIN) {
                    pk.u[0] = f2b(pos[3*sm]); pk.u[1] = f2b(pos[3*sm+1]);
                    pk.u[2] = f2b(pos[3*sm+2]); pk.u[3] = f2b(area[sm]);
                    #pragma unroll
                    for (int j = 0; j < 8; ++j) pk.u[4+j] = f2b(info[j]);
                } else {
                    float dx = pos[3*si]   - pos[3*ri];
                    float dy = pos[3*si+1] - pos[3*ri+1];
                    float dz = pos[3*si+2] - pos[3*ri+2];
                    float nm = sqrtf(dx*dx + dy*dy + dz*dz);
                    pk.u[0]=f2b(dx); pk.u[1]=f2b(dy); pk.u[2]=f2b(dz); pk.u[3]=f2b(nm);
                }
            }
        } else if (ASRC == A_NODE && k0 >= 128) {
            if (valid) {
                float4* sp = (float4*)(aggp + (size_t)sm * 128 + (k0 - 128) + sh * 16);
                float4 a0 = sp[0], a1 = sp[1], a2 = sp[2], a3 = sp[3];
                float tf[16] = {a0.x,a0.y,a0.z,a0.w, a1.x,a1.y,a1.z,a1.w,
                                a2.x,a2.y,a2.z,a2.w, a3.x,a3.y,a3.z,a3.w};
                #pragma unroll
                for (int j = 0; j < 16; ++j) pk.u[j] = f2b(tf[j]);
                float4 z = make_float4(0.f, 0.f, 0.f, 0.f);
                sp[0] = z; sp[1] = z; sp[2] = z; sp[3] = z;   // zero for next layer
            } else {
                #pragma unroll
                for (int j = 0; j < 16; ++j) pk.u[j] = 0;
            }
        } else {
            const U16* s;
            if (ASRC == A_BF16)      s = Af + (size_t)sm * K1 + k0;
            else if (ASRC == A_EDGE) {
                if (k0 < 128)        s = Vh + (size_t)si * 128 + k0;
                else if (k0 < 256)   s = Vh + (size_t)ri * 128 + (k0 - 128);
                else                 s = Ehp + (size_t)sm * 128 + (k0 - 256);
            } else                   s = Vh + (size_t)sm * 128 + k0;  // A_NODE low
            s += sh * 16;
            if (valid) { pk.v[0] = ((const int4*)s)[0]; pk.v[1] = ((const int4*)s)[1]; }
            else { pk.v[0] = make_int4(0,0,0,0); pk.v[1] = make_int4(0,0,0,0); }
        }
        *(int4*)&As[sr][sh * 16]     = pk.v[0];
        *(int4*)&As[sr][sh * 16 + 8] = pk.v[1];
    };

    auto frag_compute = [&](const U16* ab, int astr, int koff) {
        short8 wf[4], af[4];
        #pragma unroll
        for (int g = 0; g < 4; ++g)
            wf[g] = *(const short8*)&Bs[wn + g*16 + l16][quad * 8];
        #pragma unroll
        for (int g = 0; g < 4; ++g)
            af[g] = *(const short8*)(ab + (size_t)(wm + g*16 + l16) * astr + koff + quad * 8);
        #pragma unroll
        for (int wg = 0; wg < 4; ++wg)
            #pragma unroll
            for (int ag = 0; ag < 4; ++ag)
                acc[wg][ag] = __builtin_amdgcn_mfma_f32_16x16x32_bf16(
                    wf[wg], af[ag], acc[wg][ag], 0, 0, 0);
    };

    auto hwrite = [&](const float* bias) {   // bias + relu -> Hs (bf16)
        #pragma unroll
        for (int wg = 0; wg < 4; ++wg) {
            f32x4 bv = *(const f32x4*)&bias[wn + wg*16 + quad*4];
            #pragma unroll
            for (int ag = 0; ag < 4; ++ag) {
                int m  = wm + ag*16 + l16;
                int n0 = wn + wg*16 + quad*4;
                union { U16 u[4]; uint2 q; } pk;
                #pragma unroll
                for (int rg = 0; rg < 4; ++rg)
                    pk.u[rg] = f2b(fmaxf(acc[wg][ag][rg] + bv[rg], 0.f));
                *(uint2*)&Hs[m][n0] = pk.q;
            }
        }
    };

    // ---- phase 1
    zacc();
    for (int k0 = 0; k0 < K1; k0 += 32) {
        stage_A(k0);
        stage_W(W1, K1, k0);
        __syncthreads();
        frag_compute(&As[0][0], 40, 0);
        __syncthreads();
    }
    hwrite(b1);
    __syncthreads();

    // ---- phase 2
    zacc();
    for (int k0 = 0; k0 < 128; k0 += 32) {
        stage_W(W2, 128, k0);
        __syncthreads();
        frag_compute(&Hs[0][0], 132, k0);
        __syncthreads();
    }

    if (EPI == EPI_DEC) {      // decoder: h2 -> Hs, then dot with w3f
        hwrite(b2);
        __syncthreads();
        int mg = row0 + sr;
        float v = 0.f;
        if (mg < M) {
            const U16* hr = &Hs[sr][sh * 64];
            const float* wr = w3f + sh * 64;
            #pragma unroll
            for (int j = 0; j < 64; ++j) v += b2f(hr[j]) * wr[j];
        }
        v += __shfl_xor(v, 1);
        if (sh == 0 && mg < M) outf[mg] = v + b3[0];
        return;
    }

    hwrite(b2);
    __syncthreads();

    // ---- phase 3
    zacc();
    for (int k0 = 0; k0 < 128; k0 += 32) {
        stage_W(W3, 128, k0);
        __syncthreads();
        frag_compute(&Hs[0][0], 132, k0);
        __syncthreads();
    }

    // ---- epilogue (no relu): EPI_F store; EPI_EDGE/NODE residual + mirror
    f32x4 bvs[4];
    #pragma unroll
    for (int wg = 0; wg < 4; ++wg)
        bvs[wg] = *(const f32x4*)&b3[wn + wg*16 + quad*4];
    #pragma unroll
    for (int ag = 0; ag < 4; ++ag) {
        int mg = row0 + wm + ag*16 + l16;
        if (mg >= M) continue;
        int sv = 0;
        if (EPI == EPI_EDGE) sv = edges[2 * mg];
        #pragma unroll
        for (int wg = 0; wg < 4; ++wg) {
            int n0 = wn + wg*16 + quad*4;
            f32x4 v;
            #pragma unroll
            for (int rg = 0; rg < 4; ++rg) v[rg] = acc[wg][ag][rg] + bvs[wg][rg];
            size_t o = (size_t)mg * 128 + n0;
            if (EPI == EPI_F) {
                *(f32x4*)&outf[o] = v;
            } else {
                f32x4 c = *(f32x4*)&outf[o];
                c += v;
                *(f32x4*)&outf[o] = c;
                union { U16 u[4]; uint2 q; } pk;
                #pragma unroll
                for (int rg = 0; rg < 4; ++rg) pk.u[rg] = f2b(c[rg]);
                *(uint2*)&outh[o] = pk.q;
                if (EPI == EPI_EDGE) {
                    #pragma unroll
                    for (int rg = 0; rg < 4; ++rg)
                        atomicAdd(&aggp[(size_t)sv * 128 + n0 + rg], v[rg]);
                }
            }
        }
    }
}

// in-place LayerNorm over D=128 on fp32 master + bf16 mirror
__global__ __launch_bounds__(256)
void ln_kernel(float* __restrict__ X, const float* __restrict__ g,
               const float* __restrict__ b, U16* __restrict__ Xh, int rows)
{
    int row  = blockIdx.x * 4 + (threadIdx.x >> 6);
    int lane = threadIdx.x & 63;
    if (row >= rows) return;
    float x0 = X[row * DD + lane];
    float x1 = X[row * DD + 64 + lane];
    float s = x0 + x1, q = x0 * x0 + x1 * x1;
    #pragma unroll
    for (int off = 32; off; off >>= 1) {
        s += __shfl_xor(s, off);
        q += __shfl_xor(q, off);
    }
    float mu  = s * (1.f / 128.f);
    float var = q * (1.f / 128.f) - mu * mu;
    float inv = rsqrtf(var + 1e-5f);
    float y0 = (x0 - mu) * inv * g[lane]      + b[lane];
    float y1 = (x1 - mu) * inv * g[64 + lane] + b[64 + lane];
    X[row * DD + lane]       = y0;
    X[row * DD + 64 + lane]  = y1;
    Xh[row * DD + lane]      = f2b(y0);
    Xh[row * DD + 64 + lane] = f2b(y1);
}

extern "C" void kernel_launch(void* const* d_in, const int* in_sizes, int n_in,
                              void* d_out, int out_size, void* d_ws, size_t ws_size,
                              hipStream_t stream)
{
    (void)in_sizes; (void)n_in; (void)out_size; (void)ws_size;

    const float* pos   = (const float*)d_in[0];
    const float* area  = (const float*)d_in[1];
    const float* info  = (const float*)d_in[2];
    const int*   edges = (const int*)d_in[3];
    const float* fv_w1 = (const float*)d_in[4];
    const float* fv_b1 = (const float*)d_in[5];
    const float* fv_w2 = (const float*)d_in[6];
    const float* fv_b2 = (const float*)d_in[7];
    const float* fv_w3 = (const float*)d_in[8];
    const float* fv_b3 = (const float*)d_in[9];
    const float* fv_g  = (const float*)d_in[10];
    const float* fv_bt = (const float*)d_in[11];
    const float* fe_w1 = (const float*)d_in[12];
    const float* fe_b1 = (const float*)d_in[13];
    const float* fe_w2 = (const float*)d_in[14];
    const float* fe_b2 = (const float*)d_in[15];
    const float* fe_w3 = (const float*)d_in[16];
    const float* fe_b3 = (const float*)d_in[17];
    const float* fe_g  = (const float*)d_in[18];
    const float* fe_bt = (const float*)d_in[19];
    const float* ge_w1 = (const float*)d_in[20];
    const float* ge_b1 = (const float*)d_in[21];
    const float* ge_w2 = (const float*)d_in[22];
    const float* ge_b2 = (const float*)d_in[23];
    const float* ge_w3 = (const float*)d_in[24];
    const float* ge_b3 = (const float*)d_in[25];
    const float* gn_w1 = (const float*)d_in[26];
    const float* gn_b1 = (const float*)d_in[27];
    const float* gn_w2 = (const float*)d_in[28];
    const float* gn_b2 = (const float*)d_in[29];
    const float* gn_w3 = (const float*)d_in[30];
    const float* gn_b3 = (const float*)d_in[31];
    const float* de_w1 = (const float*)d_in[32];
    const float* de_b1 = (const float*)d_in[33];
    const float* de_w2 = (const float*)d_in[34];
    const float* de_b2 = (const float*)d_in[35];
    const float* de_w3 = (const float*)d_in[36];
    const float* de_b3 = (const float*)d_in[37];

    // workspace layout (~48.2 MB)
    char* p = (char*)d_ws;
    float* Vf   = (float*)p;  p += (size_t)N_NODE * 128 * 4;
    float* Ef   = (float*)p;  p += (size_t)N_EDGE * 128 * 4;
    float* aggp = (float*)p;  p += (size_t)N_NODE * 128 * 4;
    U16*  Vh    = (U16*)p;    p += (size_t)N_NODE * 128 * 2;
    U16*  Eh    = (U16*)p;    p += (size_t)N_EDGE * 128 * 2;
    U16*  Wt    = (U16*)p;

    const int gbE = (N_EDGE + 127) / 128;   // 313  (BM=128, 256 thr)
    const int gbN = (N_NODE + 63) / 64;     // 157  (BM=64, 128 thr)

    wprep<<<566, 256, 0, stream>>>(fv_w1, fv_w2, fv_w3, fe_w1, fe_w2, fe_w3,
                                   ge_w1, ge_w2, ge_w3, gn_w1, gn_w2, gn_w3,
                                   de_w1, de_w2, Wt);
    hipMemsetAsync(aggp, 0, (size_t)N_NODE * 128 * sizeof(float), stream);

    // edge encoder (eraw fused into phase-1 staging) -> Ef; LN -> Ef + Eh
    mlp3<A_ERAW, EPI_F, 128><<<gbE, 256, 0, stream>>>(
        nullptr, 32, Wt + OFF_FE1, fe_b1, Wt + OFF_FE2, fe_b2, Wt + OFF_FE3, fe_b3,
        nullptr, Ef, nullptr, edges, nullptr, nullptr, pos, nullptr, nullptr, nullptr, N_EDGE);
    ln_kernel<<<(N_EDGE + 3) / 4, 256, 0, stream>>>(Ef, fe_g, fe_bt, Eh, N_EDGE);

    // node encoder (encin fused) -> Vf; LN -> Vf + Vh
    mlp3<A_ENCIN, EPI_F, 64><<<gbN, 128, 0, stream>>>(
        nullptr, 32, Wt + OFF_FV1, fv_b1, Wt + OFF_FV2, fv_b2, Wt + OFF_FV3, fv_b3,
        nullptr, Vf, nullptr, nullptr, nullptr, nullptr, pos, area, info, nullptr, N_NODE);
    ln_kernel<<<(N_NODE + 3) / 4, 256, 0, stream>>>(Vf, fv_g, fv_bt, Vh, N_NODE);

    // 15 GNN layers: one fused edge kernel + one fused node kernel each
    for (int l = 0; l < N_LAYER; ++l) {
        mlp3<A_EDGE, EPI_EDGE, 128><<<gbE, 256, 0, stream>>>(
            nullptr, 384,
            Wt + OFF_GE1 + (size_t)l * 49152, ge_b1 + (size_t)l * 128,
            Wt + OFF_GE2 + (size_t)l * 16384, ge_b2 + (size_t)l * 128,
            Wt + OFF_GE3 + (size_t)l * 16384, ge_b3 + (size_t)l * 128,
            Eh, Ef, aggp, edges, Vh, Eh, nullptr, nullptr, nullptr, nullptr, N_EDGE);
        mlp3<A_NODE, EPI_NODE, 64><<<gbN, 128, 0, stream>>>(
            nullptr, 256,
            Wt + OFF_GN1 + (size_t)l * 32768, gn_b1 + (size_t)l * 128,
            Wt + OFF_GN2 + (size_t)l * 16384, gn_b2 + (size_t)l * 128,
            Wt + OFF_GN3 + (size_t)l * 16384, gn_b3 + (size_t)l * 128,
            Vh, Vf, aggp, nullptr, Vh, nullptr, nullptr, nullptr, nullptr, nullptr, N_NODE);
    }

    // decoder: 2 GEMM phases + final dot, one kernel
    mlp3<A_BF16, EPI_DEC, 64><<<gbN, 128, 0, stream>>>(
        Vh, 128, Wt + OFF_DE1, de_b1, Wt + OFF_DE2, de_b2, nullptr, de_b3,
        nullptr, (float*)d_out, nullptr, nullptr, nullptr, nullptr,
        nullptr, nullptr, nullptr, de_w3, N_NODE);
}

// Round 6
// 1199.890 us; speedup vs baseline: 3.9400x; 1.6092x over previous
//
#include <hip/hip_runtime.h>

#define DD 128
#define N_NODE 10000
#define N_EDGE 40000
#define N_LAYER 15

typedef unsigned short U16;
typedef __attribute__((ext_vector_type(8))) short short8;
typedef __attribute__((ext_vector_type(4))) float f32x4;

enum { A_BF16 = 0, A_EDGE, A_NODE, A_ENCIN, A_ERAW };
enum { EPI_F = 0, EPI_EDGE, EPI_NODE, EPI_DEC };

// Wt layout offsets (bf16 elements), [n=128][Kpad] per matrix
#define OFF_FV1 0
#define OFF_FV2 4096
#define OFF_FV3 20480
#define OFF_FE1 36864
#define OFF_FE2 40960
#define OFF_FE3 57344
#define OFF_GE1 73728     /* stride 49152 (Kpad=384) */
#define OFF_GE2 811008    /* stride 16384 */
#define OFF_GE3 1056768
#define OFF_GN1 1302528   /* stride 32768 (Kpad=256) */
#define OFF_GN2 1794048
#define OFF_GN3 2039808
#define OFF_DE1 2285568
#define OFF_DE2 2301952
#define WT_TOTAL 2318336

static __device__ __forceinline__ U16 f2b(float f) {
    union { float f; unsigned u; } x; x.f = f;
    unsigned u = x.u;
    return (U16)((u + 0x7fffu + ((u >> 16) & 1u)) >> 16);
}
static __device__ __forceinline__ float b2f(U16 u) {
    union { unsigned u; float f; } x; x.u = ((unsigned)u) << 16;
    return x.f;
}

// ---------------- weight transpose+cast: W[K][128] f32 -> Wt[n][Kpad] bf16 ----
__global__ __launch_bounds__(256)
void wprep(const float* fv1, const float* fv2, const float* fv3,
           const float* fe1, const float* fe2, const float* fe3,
           const float* ge1, const float* ge2, const float* ge3,
           const float* gn1, const float* gn2, const float* gn3,
           const float* de1, const float* de2, U16* Wt)
{
    int b = blockIdx.x;
    const float* src; U16* dst; int K, Kpad, k0;
    if      (b < 1)   { src = fv1; K = 12;  Kpad = 32;  dst = Wt + OFF_FV1; k0 = b * 32; }
    else if (b < 5)   { src = fv2; K = 128; Kpad = 128; dst = Wt + OFF_FV2; k0 = (b-1)*32; }
    else if (b < 9)   { src = fv3; K = 128; Kpad = 128; dst = Wt + OFF_FV3; k0 = (b-5)*32; }
    else if (b < 10)  { src = fe1; K = 4;   Kpad = 32;  dst = Wt + OFF_FE1; k0 = (b-9)*32; }
    else if (b < 14)  { src = fe2; K = 128; Kpad = 128; dst = Wt + OFF_FE2; k0 = (b-10)*32; }
    else if (b < 18)  { src = fe3; K = 128; Kpad = 128; dst = Wt + OFF_FE3; k0 = (b-14)*32; }
    else if (b < 198) { int r = b-18,  mi = r/12, s = r%12; src = ge1 + (size_t)mi*384*128; K = 384; Kpad = 384; dst = Wt + OFF_GE1 + (size_t)mi*49152; k0 = s*32; }
    else if (b < 258) { int r = b-198, mi = r/4,  s = r%4;  src = ge2 + (size_t)mi*16384;   K = 128; Kpad = 128; dst = Wt + OFF_GE2 + (size_t)mi*16384; k0 = s*32; }
    else if (b < 318) { int r = b-258, mi = r/4,  s = r%4;  src = ge3 + (size_t)mi*16384;   K = 128; Kpad = 128; dst = Wt + OFF_GE3 + (size_t)mi*16384; k0 = s*32; }
    else if (b < 438) { int r = b-318, mi = r/8,  s = r%8;  src = gn1 + (size_t)mi*32768;   K = 256; Kpad = 256; dst = Wt + OFF_GN1 + (size_t)mi*32768; k0 = s*32; }
    else if (b < 498) { int r = b-438, mi = r/4,  s = r%4;  src = gn2 + (size_t)mi*16384;   K = 128; Kpad = 128; dst = Wt + OFF_GN2 + (size_t)mi*16384; k0 = s*32; }
    else if (b < 558) { int r = b-498, mi = r/4,  s = r%4;  src = gn3 + (size_t)mi*16384;   K = 128; Kpad = 128; dst = Wt + OFF_GN3 + (size_t)mi*16384; k0 = s*32; }
    else if (b < 562) { src = de1; K = 128; Kpad = 128; dst = Wt + OFF_DE1; k0 = (b-558)*32; }
    else              { src = de2; K = 128; Kpad = 128; dst = Wt + OFF_DE2; k0 = (b-562)*32; }

    __shared__ float T[32][129];
    #pragma unroll
    for (int i = 0; i < 16; ++i) {
        int l = threadIdx.x + i * 256;
        int kk = l >> 7, n = l & 127;
        int kg = k0 + kk;
        T[kk][n] = (kg < K) ? src[(size_t)kg * 128 + n] : 0.f;
    }
    __syncthreads();
    int n = threadIdx.x >> 1, h = threadIdx.x & 1;
    union { U16 u[16]; int4 v[2]; } o;
    #pragma unroll
    for (int j = 0; j < 16; ++j) o.u[j] = f2b(T[h * 16 + j][n]);
    int4* d = (int4*)(dst + (size_t)n * Kpad + k0 + h * 16);
    d[0] = o.v[0]; d[1] = o.v[1];
}

// ---------------- CSR build (sender-sorted) ----------------------------------
__global__ __launch_bounds__(256)
void csr_hist(const int* __restrict__ edges, int* __restrict__ cnt, int Eg)
{
    int e = blockIdx.x * 256 + threadIdx.x;
    if (e < Eg) atomicAdd(&cnt[edges[2 * e]], 1);
}

__global__ __launch_bounds__(256)
void csr_scan(const int* __restrict__ cnt, int* __restrict__ rowptr,
              int* __restrict__ cursor, int n)
{
    __shared__ int ps[256];
    int t = threadIdx.x, base = t * 40;
    int s = 0;
    for (int j = 0; j < 40; ++j) if (base + j < n) s += cnt[base + j];
    ps[t] = s; __syncthreads();
    for (int off = 1; off < 256; off <<= 1) {
        int v = (t >= off) ? ps[t - off] : 0;
        __syncthreads();
        ps[t] += v;
        __syncthreads();
    }
    int run = ps[t] - s;   // exclusive prefix
    for (int j = 0; j < 40; ++j) {
        if (base + j < n) {
            rowptr[base + j] = run;
            cursor[base + j] = run;
            run += cnt[base + j];
        }
    }
    if (t == 255) rowptr[n] = ps[255];
}

__global__ __launch_bounds__(256)
void csr_scatter(const int* __restrict__ edges, int* __restrict__ cursor,
                 int* __restrict__ spos, int Eg)
{
    int e = blockIdx.x * 256 + threadIdx.x;
    if (e < Eg) spos[e] = atomicAdd(&cursor[edges[2 * e]], 1);
}

// ---------------- fused 3-layer MLP (MFMA, W-as-A orientation) ---------------
// BM=64 rows/block, 256 threads = 4 waves (2x2), wave = 32 rows x 64 cols.
// Double-buffered As/Bs, 1 barrier per k-iter. Phases chain through Hs (LDS).
template<int ASRC, int EPI>
__global__ __launch_bounds__(256)
void mlp3(const U16* __restrict__ Af, int K1,
          const U16* __restrict__ W1, const float* __restrict__ b1,
          const U16* __restrict__ W2, const float* __restrict__ b2,
          const U16* __restrict__ W3, const float* __restrict__ b3,
          U16* __restrict__ outh, float* __restrict__ outf,
          const int* __restrict__ edges, const int* __restrict__ rowptr,
          const int* __restrict__ spos, float* __restrict__ eEs,
          const U16* __restrict__ Vh, const U16* __restrict__ Ehp,
          const float* __restrict__ pos, const float* __restrict__ area,
          const float* __restrict__ info, const float* __restrict__ w3f,
          int M)
{
    __shared__ U16 As[2][64][40];    // [buf][m][k]
    __shared__ U16 Bs[2][128][40];   // [buf][n][k]
    __shared__ U16 Hs[64][132];      // inter-phase activations [m][n]

    const int tid  = threadIdx.x;
    const int row0 = blockIdx.x * 64;
    const int wave = tid >> 6, lane = tid & 63;
    const int quad = lane >> 4, l16 = lane & 15;
    const int wm = (wave >> 1) * 32;           // wave m-offset
    const int wn = (wave & 1) * 64;            // wave n-offset
    const int sr = tid >> 2, sh = tid & 3;     // A staging: row, 8-col chunk
    const int br = tid >> 1, bh = tid & 1;     // W staging: row, 16-col half
    const int sm = row0 + sr;
    const bool valid = (sm < M);

    int si = 0, ri = 0, jbeg = 0, jend = 0;
    if ((ASRC == A_EDGE || ASRC == A_ERAW) && valid) {
        si = edges[2 * sm]; ri = edges[2 * sm + 1];
    }
    if (ASRC == A_NODE && valid) { jbeg = rowptr[sm]; jend = rowptr[sm + 1]; }

    f32x4 acc[4][2];   // [wg][ag]: n = wn+wg*16+quad*4+rg, m = wm+ag*16+l16

    auto zacc = [&] {
        #pragma unroll
        for (int i = 0; i < 4; ++i)
            #pragma unroll
            for (int j = 0; j < 2; ++j) acc[i][j] = (f32x4)0.f;
    };

    auto stageA = [&](int c, int b) {
        if (ASRC == A_ENCIN || ASRC == A_ERAW) {
            union { U16 u[8]; int4 v; } pk;
            #pragma unroll
            for (int j = 0; j < 8; ++j) pk.u[j] = 0;
            if (valid) {
                if (ASRC == A_ENCIN) {
                    #pragma unroll
                    for (int j = 0; j < 8; ++j) {
                        int col = sh * 8 + j;
                        float x = 0.f;
                        if (col < 3)       x = pos[3 * sm + col];
                        else if (col == 3) x = area[sm];
                        else if (col < 12) x = info[col - 4];
                        pk.u[j] = f2b(x);
                    }
                } else if (sh == 0) {
                    float dx = pos[3*si]   - pos[3*ri];
                    float dy = pos[3*si+1] - pos[3*ri+1];
                    float dz = pos[3*si+2] - pos[3*ri+2];
                    float nm = sqrtf(dx*dx + dy*dy + dz*dz);
                    pk.u[0] = f2b(dx); pk.u[1] = f2b(dy);
                    pk.u[2] = f2b(dz); pk.u[3] = f2b(nm);
                }
            }
            *(int4*)&As[b][sr][sh * 8] = pk.v;
        } else if (ASRC == A_NODE && c >= 4) {
            // segmented sum over sender-sorted e_emb rows (fp32), then bf16
            float a[8];
            #pragma unroll
            for (int i = 0; i < 8; ++i) a[i] = 0.f;
            if (valid) {
                const float* base = eEs + (c - 4) * 32 + sh * 8;
                for (int j = jbeg; j < jend; ++j) {
                    const float4* r = (const float4*)(base + (size_t)j * 128);
                    float4 x0 = r[0], x1 = r[1];
                    a[0]+=x0.x; a[1]+=x0.y; a[2]+=x0.z; a[3]+=x0.w;
                    a[4]+=x1.x; a[5]+=x1.y; a[6]+=x1.z; a[7]+=x1.w;
                }
            }
            union { U16 u[8]; int4 v; } pk;
            #pragma unroll
            for (int i = 0; i < 8; ++i) pk.u[i] = f2b(a[i]);
            *(int4*)&As[b][sr][sh * 8] = pk.v;
        } else {
            const U16* s;
            if (ASRC == A_BF16)        s = Af + (size_t)sm * K1 + c * 32;
            else if (ASRC == A_EDGE) {
                if (c < 4)             s = Vh  + (size_t)si * 128 + c * 32;
                else if (c < 8)        s = Vh  + (size_t)ri * 128 + (c - 4) * 32;
                else                   s = Ehp + (size_t)sm * 128 + (c - 8) * 32;
            } else                     s = Vh  + (size_t)sm * 128 + c * 32;  // A_NODE c<4
            int4 w = valid ? *(const int4*)(s + sh * 8) : make_int4(0,0,0,0);
            *(int4*)&As[b][sr][sh * 8] = w;
        }
    };

    auto stageW = [&](const U16* W, int Kw, int k0, int b) {
        const U16* s = W + (size_t)br * Kw + k0 + bh * 16;
        *(int4*)&Bs[b][br][bh * 16]     = ((const int4*)s)[0];
        *(int4*)&Bs[b][br][bh * 16 + 8] = ((const int4*)s)[1];
    };

    auto mf = [&](const U16* Ap, int astr, const U16* Bp) {
        short8 wf[4], af[2];
        #pragma unroll
        for (int g = 0; g < 4; ++g)
            wf[g] = *(const short8*)(Bp + (size_t)(wn + g*16 + l16) * 40 + quad * 8);
        #pragma unroll
        for (int g = 0; g < 2; ++g)
            af[g] = *(const short8*)(Ap + (size_t)(wm + g*16 + l16) * astr + quad * 8);
        #pragma unroll
        for (int wg = 0; wg < 4; ++wg)
            #pragma unroll
            for (int ag = 0; ag < 2; ++ag)
                acc[wg][ag] = __builtin_amdgcn_mfma_f32_16x16x32_bf16(
                    wf[wg], af[ag], acc[wg][ag], 0, 0, 0);
    };

    auto hwrite = [&](const float* bias) {
        #pragma unroll
        for (int wg = 0; wg < 4; ++wg) {
            f32x4 bv = *(const f32x4*)&bias[wn + wg*16 + quad*4];
            #pragma unroll
            for (int ag = 0; ag < 2; ++ag) {
                int m  = wm + ag*16 + l16;
                int n0 = wn + wg*16 + quad*4;
                union { U16 u[4]; uint2 q; } pk;
                #pragma unroll
                for (int rg = 0; rg < 4; ++rg)
                    pk.u[rg] = f2b(fmaxf(acc[wg][ag][rg] + bv[rg], 0.f));
                *(uint2*)&Hs[m][n0] = pk.q;
            }
        }
    };

    // ---- phase 1 (dbuf, 1 barrier/iter)
    zacc();
    const int C1 = K1 / 32;
    stageA(0, 0); stageW(W1, K1, 0, 0);
    for (int c = 0; c < C1; ++c) {
        __syncthreads();
        if (c + 1 < C1) { stageA(c + 1, (c+1)&1); stageW(W1, K1, (c+1)*32, (c+1)&1); }
        mf(&As[c & 1][0][0], 40, &Bs[c & 1][0][0]);
    }
    hwrite(b1);
    __syncthreads();

    // ---- phase 2
    zacc();
    stageW(W2, 128, 0, 0);
    for (int c = 0; c < 4; ++c) {
        __syncthreads();
        if (c + 1 < 4) stageW(W2, 128, (c+1)*32, (c+1)&1);
        mf(&Hs[0][c * 32], 132, &Bs[c & 1][0][0]);
    }

    if (EPI == EPI_DEC) {        // decoder: h2 -> Hs, then dot with w3f
        hwrite(b2);
        __syncthreads();
        int mg = row0 + sr;
        float v = 0.f;
        if (mg < M) {
            const U16* hr = &Hs[sr][sh * 32];
            const float* wr = w3f + sh * 32;
            #pragma unroll
            for (int j = 0; j < 32; ++j) v += b2f(hr[j]) * wr[j];
        }
        v += __shfl_xor(v, 1);
        v += __shfl_xor(v, 2);
        if (sh == 0 && mg < M) outf[mg] = v + b3[0];
        return;
    }

    hwrite(b2);
    __syncthreads();

    // ---- phase 3
    zacc();
    stageW(W3, 128, 0, 0);
    for (int c = 0; c < 4; ++c) {
        __syncthreads();
        if (c + 1 < 4) stageW(W3, 128, (c+1)*32, (c+1)&1);
        mf(&Hs[0][c * 32], 132, &Bs[c & 1][0][0]);
    }

    // ---- epilogue (no relu)
    f32x4 bvs[4];
    #pragma unroll
    for (int wg = 0; wg < 4; ++wg)
        bvs[wg] = *(const f32x4*)&b3[wn + wg*16 + quad*4];
    #pragma unroll
    for (int ag = 0; ag < 2; ++ag) {
        int mg = row0 + wm + ag*16 + l16;
        if (mg >= M) continue;
        int sp = 0;
        if (EPI == EPI_EDGE) sp = spos[mg];
        #pragma unroll
        for (int wg = 0; wg < 4; ++wg) {
            int n0 = wn + wg*16 + quad*4;
            f32x4 v;
            #pragma unroll
            for (int rg = 0; rg < 4; ++rg) v[rg] = acc[wg][ag][rg] + bvs[wg][rg];
            size_t o = (size_t)mg * 128 + n0;
            if (EPI == EPI_F) {
                *(f32x4*)&outf[o] = v;
            } else {
                f32x4 c = *(f32x4*)&outf[o];
                c += v;
                *(f32x4*)&outf[o] = c;
                union { U16 u[4]; uint2 q; } pk;
                #pragma unroll
                for (int rg = 0; rg < 4; ++rg) pk.u[rg] = f2b(c[rg]);
                *(uint2*)&outh[o] = pk.q;
                if (EPI == EPI_EDGE)
                    *(f32x4*)&eEs[(size_t)sp * 128 + n0] = v;   // sorted e_emb
            }
        }
    }
}

// in-place LayerNorm over D=128 on fp32 master + bf16 mirror
__global__ __launch_bounds__(256)
void ln_kernel(float* __restrict__ X, const float* __restrict__ g,
               const float* __restrict__ b, U16* __restrict__ Xh, int rows)
{
    int row  = blockIdx.x * 4 + (threadIdx.x >> 6);
    int lane = threadIdx.x & 63;
    if (row >= rows) return;
    float x0 = X[row * DD + lane];
    float x1 = X[row * DD + 64 + lane];
    float s = x0 + x1, q = x0 * x0 + x1 * x1;
    #pragma unroll
    for (int off = 32; off; off >>= 1) {
        s += __shfl_xor(s, off);
        q += __shfl_xor(q, off);
    }
    float mu  = s * (1.f / 128.f);
    float var = q * (1.f / 128.f) - mu * mu;
    float inv = rsqrtf(var + 1e-5f);
    float y0 = (x0 - mu) * inv * g[lane]      + b[lane];
    float y1 = (x1 - mu) * inv * g[64 + lane] + b[64 + lane];
    X[row * DD + lane]       = y0;
    X[row * DD + 64 + lane]  = y1;
    Xh[row * DD + lane]      = f2b(y0);
    Xh[row * DD + 64 + lane] = f2b(y1);
}

extern "C" void kernel_launch(void* const* d_in, const int* in_sizes, int n_in,
                              void* d_out, int out_size, void* d_ws, size_t ws_size,
                              hipStream_t stream)
{
    (void)in_sizes; (void)n_in; (void)out_size; (void)ws_size;

    const float* pos   = (const float*)d_in[0];
    const float* area  = (const float*)d_in[1];
    const float* info  = (const float*)d_in[2];
    const int*   edges = (const int*)d_in[3];
    const float* fv_w1 = (const float*)d_in[4];
    const float* fv_b1 = (const float*)d_in[5];
    const float* fv_w2 = (const float*)d_in[6];
    const float* fv_b2 = (const float*)d_in[7];
    const float* fv_w3 = (const float*)d_in[8];
    const float* fv_b3 = (const float*)d_in[9];
    const float* fv_g  = (const float*)d_in[10];
    const float* fv_bt = (const float*)d_in[11];
    const float* fe_w1 = (const float*)d_in[12];
    const float* fe_b1 = (const float*)d_in[13];
    const float* fe_w2 = (const float*)d_in[14];
    const float* fe_b2 = (const float*)d_in[15];
    const float* fe_w3 = (const float*)d_in[16];
    const float* fe_b3 = (const float*)d_in[17];
    const float* fe_g  = (const float*)d_in[18];
    const float* fe_bt = (const float*)d_in[19];
    const float* ge_w1 = (const float*)d_in[20];
    const float* ge_b1 = (const float*)d_in[21];
    const float* ge_w2 = (const float*)d_in[22];
    const float* ge_b2 = (const float*)d_in[23];
    const float* ge_w3 = (const float*)d_in[24];
    const float* ge_b3 = (const float*)d_in[25];
    const float* gn_w1 = (const float*)d_in[26];
    const float* gn_b1 = (const float*)d_in[27];
    const float* gn_w2 = (const float*)d_in[28];
    const float* gn_b2 = (const float*)d_in[29];
    const float* gn_w3 = (const float*)d_in[30];
    const float* gn_b3 = (const float*)d_in[31];
    const float* de_w1 = (const float*)d_in[32];
    const float* de_b1 = (const float*)d_in[33];
    const float* de_w2 = (const float*)d_in[34];
    const float* de_b2 = (const float*)d_in[35];
    const float* de_w3 = (const float*)d_in[36];
    const float* de_b3 = (const float*)d_in[37];

    // workspace layout (~64 MB)
    char* p = (char*)d_ws;
    float* Vf   = (float*)p;  p += (size_t)N_NODE * 128 * 4;
    float* Ef   = (float*)p;  p += (size_t)N_EDGE * 128 * 4;
    float* eEs  = (float*)p;  p += (size_t)N_EDGE * 128 * 4;
    U16*  Vh    = (U16*)p;    p += (size_t)N_NODE * 128 * 2;
    U16*  Eh    = (U16*)p;    p += (size_t)N_EDGE * 128 * 2;
    U16*  Wt    = (U16*)p;    p += (size_t)WT_TOTAL * 2;
    int*  rowptr = (int*)p;   p += (size_t)(N_NODE + 4) * 4;
    int*  cursor = (int*)p;   p += (size_t)N_NODE * 4;
    int*  cnt    = (int*)p;   p += (size_t)N_NODE * 4;
    int*  spos   = (int*)p;   p += (size_t)N_EDGE * 4;

    const int gbE = (N_EDGE + 63) / 64;   // 625
    const int gbN = (N_NODE + 63) / 64;   // 157

    // ---- prep: weights, CSR
    wprep<<<566, 256, 0, stream>>>(fv_w1, fv_w2, fv_w3, fe_w1, fe_w2, fe_w3,
                                   ge_w1, ge_w2, ge_w3, gn_w1, gn_w2, gn_w3,
                                   de_w1, de_w2, Wt);
    hipMemsetAsync(cnt, 0, (size_t)N_NODE * 4, stream);
    csr_hist<<<(N_EDGE + 255) / 256, 256, 0, stream>>>(edges, cnt, N_EDGE);
    csr_scan<<<1, 256, 0, stream>>>(cnt, rowptr, cursor, N_NODE);
    csr_scatter<<<(N_EDGE + 255) / 256, 256, 0, stream>>>(edges, cursor, spos, N_EDGE);

    // ---- edge encoder (eraw fused) -> Ef; LN -> Ef + Eh
    mlp3<A_ERAW, EPI_F><<<gbE, 256, 0, stream>>>(
        nullptr, 32, Wt + OFF_FE1, fe_b1, Wt + OFF_FE2, fe_b2, Wt + OFF_FE3, fe_b3,
        nullptr, Ef, edges, nullptr, nullptr, nullptr, nullptr, nullptr,
        pos, nullptr, nullptr, nullptr, N_EDGE);
    ln_kernel<<<(N_EDGE + 3) / 4, 256, 0, stream>>>(Ef, fe_g, fe_bt, Eh, N_EDGE);

    // ---- node encoder (encin fused) -> Vf; LN -> Vf + Vh
    mlp3<A_ENCIN, EPI_F><<<gbN, 256, 0, stream>>>(
        nullptr, 32, Wt + OFF_FV1, fv_b1, Wt + OFF_FV2, fv_b2, Wt + OFF_FV3, fv_b3,
        nullptr, Vf, nullptr, nullptr, nullptr, nullptr, nullptr, nullptr,
        pos, area, info, nullptr, N_NODE);
    ln_kernel<<<(N_NODE + 3) / 4, 256, 0, stream>>>(Vf, fv_g, fv_bt, Vh, N_NODE);

    // ---- 15 GNN layers
    for (int l = 0; l < N_LAYER; ++l) {
        mlp3<A_EDGE, EPI_EDGE><<<gbE, 256, 0, stream>>>(
            nullptr, 384,
            Wt + OFF_GE1 + (size_t)l * 49152, ge_b1 + (size_t)l * 128,
            Wt + OFF_GE2 + (size_t)l * 16384, ge_b2 + (size_t)l * 128,
            Wt + OFF_GE3 + (size_t)l * 16384, ge_b3 + (size_t)l * 128,
            Eh, Ef, edges, nullptr, spos, eEs, Vh, Eh,
            nullptr, nullptr, nullptr, nullptr, N_EDGE);
        mlp3<A_NODE, EPI_NODE><<<gbN, 256, 0, stream>>>(
            nullptr, 256,
            Wt + OFF_GN1 + (size_t)l * 32768, gn_b1 + (size_t)l * 128,
            Wt + OFF_GN2 + (size_t)l * 16384, gn_b2 + (size_t)l * 128,
            Wt + OFF_GN3 + (size_t)l * 16384, gn_b3 + (size_t)l * 128,
            Vh, Vf, nullptr, rowptr, nullptr, eEs, Vh, nullptr,
            nullptr, nullptr, nullptr, nullptr, N_NODE);
    }

    // ---- decoder
    mlp3<A_BF16, EPI_DEC><<<gbN, 256, 0, stream>>>(
        Vh, 128, Wt + OFF_DE1, de_b1, Wt + OFF_DE2, de_b2, nullptr, de_b3,
        nullptr, (float*)d_out, nullptr, nullptr, nullptr, nullptr, nullptr, nullptr,
        nullptr, nullptr, nullptr, de_w3, N_NODE);
}

// Round 7
// 1085.426 us; speedup vs baseline: 4.3555x; 1.1055x over previous
//
#include <hip/hip_runtime.h>

#define DD 128
#define N_NODE 10000
#define N_EDGE 40000
#define N_LAYER 15

typedef unsigned short U16;
typedef __attribute__((ext_vector_type(8))) short short8;
typedef __attribute__((ext_vector_type(4))) float f32x4;

enum { A_BF16 = 0, A_EDGE, A_NODE, A_ENCIN, A_ERAW };
enum { EPI_F = 0, EPI_EDGE, EPI_NODE, EPI_DEC };

// Wt layout offsets (bf16 elements), [n=128][Kpad] per matrix
#define OFF_FV1 0
#define OFF_FV2 4096
#define OFF_FV3 20480
#define OFF_FE1 36864
#define OFF_FE2 40960
#define OFF_FE3 57344
#define OFF_GE1 73728     /* stride 49152 (Kpad=384) */
#define OFF_GE2 811008    /* stride 16384 */
#define OFF_GE3 1056768
#define OFF_GN1 1302528   /* stride 32768 (Kpad=256) */
#define OFF_GN2 1794048
#define OFF_GN3 2039808
#define OFF_DE1 2285568
#define OFF_DE2 2301952
#define WT_TOTAL 2318336

static __device__ __forceinline__ U16 f2b(float f) {
    union { float f; unsigned u; } x; x.f = f;
    unsigned u = x.u;
    return (U16)((u + 0x7fffu + ((u >> 16) & 1u)) >> 16);
}
static __device__ __forceinline__ float b2f(U16 u) {
    union { unsigned u; float f; } x; x.u = ((unsigned)u) << 16;
    return x.f;
}

// workgroup barrier draining ONLY lgkmcnt: in-flight global prefetch loads
// (vmcnt) survive the barrier — this is the whole point of Round 7.
static __device__ __forceinline__ void wgb() {
    __asm__ __volatile__("s_waitcnt lgkmcnt(0)\n\ts_barrier" ::: "memory");
}

struct I4x2 { int4 a, b; };

// ---------------- weight transpose+cast: W[K][128] f32 -> Wt[n][Kpad] bf16 ----
__global__ __launch_bounds__(256)
void wprep(const float* fv1, const float* fv2, const float* fv3,
           const float* fe1, const float* fe2, const float* fe3,
           const float* ge1, const float* ge2, const float* ge3,
           const float* gn1, const float* gn2, const float* gn3,
           const float* de1, const float* de2, U16* Wt)
{
    int b = blockIdx.x;
    const float* src; U16* dst; int K, Kpad, k0;
    if      (b < 1)   { src = fv1; K = 12;  Kpad = 32;  dst = Wt + OFF_FV1; k0 = b * 32; }
    else if (b < 5)   { src = fv2; K = 128; Kpad = 128; dst = Wt + OFF_FV2; k0 = (b-1)*32; }
    else if (b < 9)   { src = fv3; K = 128; Kpad = 128; dst = Wt + OFF_FV3; k0 = (b-5)*32; }
    else if (b < 10)  { src = fe1; K = 4;   Kpad = 32;  dst = Wt + OFF_FE1; k0 = (b-9)*32; }
    else if (b < 14)  { src = fe2; K = 128; Kpad = 128; dst = Wt + OFF_FE2; k0 = (b-10)*32; }
    else if (b < 18)  { src = fe3; K = 128; Kpad = 128; dst = Wt + OFF_FE3; k0 = (b-14)*32; }
    else if (b < 198) { int r = b-18,  mi = r/12, s = r%12; src = ge1 + (size_t)mi*384*128; K = 384; Kpad = 384; dst = Wt + OFF_GE1 + (size_t)mi*49152; k0 = s*32; }
    else if (b < 258) { int r = b-198, mi = r/4,  s = r%4;  src = ge2 + (size_t)mi*16384;   K = 128; Kpad = 128; dst = Wt + OFF_GE2 + (size_t)mi*16384; k0 = s*32; }
    else if (b < 318) { int r = b-258, mi = r/4,  s = r%4;  src = ge3 + (size_t)mi*16384;   K = 128; Kpad = 128; dst = Wt + OFF_GE3 + (size_t)mi*16384; k0 = s*32; }
    else if (b < 438) { int r = b-318, mi = r/8,  s = r%8;  src = gn1 + (size_t)mi*32768;   K = 256; Kpad = 256; dst = Wt + OFF_GN1 + (size_t)mi*32768; k0 = s*32; }
    else if (b < 498) { int r = b-438, mi = r/4,  s = r%4;  src = gn2 + (size_t)mi*16384;   K = 128; Kpad = 128; dst = Wt + OFF_GN2 + (size_t)mi*16384; k0 = s*32; }
    else if (b < 558) { int r = b-498, mi = r/4,  s = r%4;  src = gn3 + (size_t)mi*16384;   K = 128; Kpad = 128; dst = Wt + OFF_GN3 + (size_t)mi*16384; k0 = s*32; }
    else if (b < 562) { src = de1; K = 128; Kpad = 128; dst = Wt + OFF_DE1; k0 = (b-558)*32; }
    else              { src = de2; K = 128; Kpad = 128; dst = Wt + OFF_DE2; k0 = (b-562)*32; }

    __shared__ float T[32][129];
    #pragma unroll
    for (int i = 0; i < 16; ++i) {
        int l = threadIdx.x + i * 256;
        int kk = l >> 7, n = l & 127;
        int kg = k0 + kk;
        T[kk][n] = (kg < K) ? src[(size_t)kg * 128 + n] : 0.f;
    }
    __syncthreads();
    int n = threadIdx.x >> 1, h = threadIdx.x & 1;
    union { U16 u[16]; int4 v[2]; } o;
    #pragma unroll
    for (int j = 0; j < 16; ++j) o.u[j] = f2b(T[h * 16 + j][n]);
    int4* d = (int4*)(dst + (size_t)n * Kpad + k0 + h * 16);
    d[0] = o.v[0]; d[1] = o.v[1];
}

// ---------------- CSR build (sender-sorted) ----------------------------------
__global__ __launch_bounds__(256)
void csr_hist(const int* __restrict__ edges, int* __restrict__ cnt, int Eg)
{
    int e = blockIdx.x * 256 + threadIdx.x;
    if (e < Eg) atomicAdd(&cnt[edges[2 * e]], 1);
}

__global__ __launch_bounds__(256)
void csr_scan(const int* __restrict__ cnt, int* __restrict__ rowptr,
              int* __restrict__ cursor, int n)
{
    __shared__ int ps[256];
    int t = threadIdx.x, base = t * 40;
    int s = 0;
    for (int j = 0; j < 40; ++j) if (base + j < n) s += cnt[base + j];
    ps[t] = s; __syncthreads();
    for (int off = 1; off < 256; off <<= 1) {
        int v = (t >= off) ? ps[t - off] : 0;
        __syncthreads();
        ps[t] += v;
        __syncthreads();
    }
    int run = ps[t] - s;   // exclusive prefix
    for (int j = 0; j < 40; ++j) {
        if (base + j < n) {
            rowptr[base + j] = run;
            cursor[base + j] = run;
            run += cnt[base + j];
        }
    }
    if (t == 255) rowptr[n] = ps[255];
}

__global__ __launch_bounds__(256)
void csr_scatter(const int* __restrict__ edges, int* __restrict__ cursor,
                 int* __restrict__ spos, int Eg)
{
    int e = blockIdx.x * 256 + threadIdx.x;
    if (e < Eg) spos[e] = atomicAdd(&cursor[edges[2 * e]], 1);
}

// ---------------- fused 3-layer MLP (MFMA, W-as-A, pipelined K-loop) ---------
// BM=64, 256 thr = 4 waves (2x2), wave = 32 rows x 64 cols.
// Register prefetch depth-2: chunk c+2 global->regs at iter c, regs->LDS at
// iter c+1, consumed at c+2. Barrier drains lgkmcnt only (wgb), so prefetch
// loads stay in flight across it.
template<int ASRC, int EPI, int K1>
__global__ __launch_bounds__(256)
void mlp3(const U16* __restrict__ Af,
          const U16* __restrict__ W1, const float* __restrict__ b1,
          const U16* __restrict__ W2, const float* __restrict__ b2,
          const U16* __restrict__ W3, const float* __restrict__ b3,
          U16* __restrict__ outh, float* __restrict__ outf,
          const int* __restrict__ edges, const int* __restrict__ rowptr,
          const int* __restrict__ spos, float* __restrict__ eEs,
          const U16* __restrict__ Vh, const U16* __restrict__ Ehp,
          const float* __restrict__ pos, const float* __restrict__ area,
          const float* __restrict__ info, const float* __restrict__ w3f,
          int M)
{
    __shared__ U16 As[2][64][40];    // [buf][m][k]
    __shared__ U16 Bs[2][128][40];   // [buf][n][k]
    __shared__ U16 Hs[64][132];      // inter-phase activations [m][n]

    const int tid  = threadIdx.x;
    const int row0 = blockIdx.x * 64;
    const int wave = tid >> 6, lane = tid & 63;
    const int quad = lane >> 4, l16 = lane & 15;
    const int wm = (wave >> 1) * 32;           // wave m-offset
    const int wn = (wave & 1) * 64;            // wave n-offset
    const int sr = tid >> 2, sh = tid & 3;     // A staging: row, 8-col chunk
    const int br = tid >> 1, bh = tid & 1;     // W staging: row, 16-col half
    const int sm = row0 + sr;
    const bool valid = (sm < M);

    int si = 0, ri = 0, jbeg = 0, jend = 0;
    if ((ASRC == A_EDGE || ASRC == A_ERAW) && valid) {
        si = edges[2 * sm]; ri = edges[2 * sm + 1];
    }
    if (ASRC == A_NODE && valid) { jbeg = rowptr[sm]; jend = rowptr[sm + 1]; }

    f32x4 acc[4][2];   // [wg][ag]: n = wn+wg*16+quad*4+rg, m = wm+ag*16+l16

    auto zacc = [&] {
        #pragma unroll
        for (int i = 0; i < 4; ++i)
            #pragma unroll
            for (int j = 0; j < 2; ++j) acc[i][j] = (f32x4)0.f;
    };

    auto ldA = [&](int c) -> int4 {
        if (ASRC == A_ENCIN || ASRC == A_ERAW) {
            union { U16 u[8]; int4 v; } pk;
            #pragma unroll
            for (int j = 0; j < 8; ++j) pk.u[j] = 0;
            if (valid) {
                if (ASRC == A_ENCIN) {
                    #pragma unroll
                    for (int j = 0; j < 8; ++j) {
                        int col = sh * 8 + j;
                        float x = 0.f;
                        if (col < 3)       x = pos[3 * sm + col];
                        else if (col == 3) x = area[sm];
                        else if (col < 12) x = info[col - 4];
                        pk.u[j] = f2b(x);
                    }
                } else if (sh == 0) {
                    float dx = pos[3*si]   - pos[3*ri];
                    float dy = pos[3*si+1] - pos[3*ri+1];
                    float dz = pos[3*si+2] - pos[3*ri+2];
                    float nm = sqrtf(dx*dx + dy*dy + dz*dz);
                    pk.u[0] = f2b(dx); pk.u[1] = f2b(dy);
                    pk.u[2] = f2b(dz); pk.u[3] = f2b(nm);
                }
            }
            return pk.v;
        } else if (ASRC == A_NODE && c >= 4) {
            // segmented sum over sender-sorted e_emb rows (fp32) -> bf16
            float a[8];
            #pragma unroll
            for (int i = 0; i < 8; ++i) a[i] = 0.f;
            if (valid) {
                const float* base = eEs + (c - 4) * 32 + sh * 8;
                for (int j = jbeg; j < jend; ++j) {
                    const float4* r = (const float4*)(base + (size_t)j * 128);
                    float4 x0 = r[0], x1 = r[1];
                    a[0]+=x0.x; a[1]+=x0.y; a[2]+=x0.z; a[3]+=x0.w;
                    a[4]+=x1.x; a[5]+=x1.y; a[6]+=x1.z; a[7]+=x1.w;
                }
            }
            union { U16 u[8]; int4 v; } pk;
            #pragma unroll
            for (int i = 0; i < 8; ++i) pk.u[i] = f2b(a[i]);
            return pk.v;
        } else {
            const U16* s;
            if (ASRC == A_BF16)        s = Af + (size_t)sm * K1 + c * 32;
            else if (ASRC == A_EDGE) {
                if (c < 4)             s = Vh  + (size_t)si * 128 + c * 32;
                else if (c < 8)        s = Vh  + (size_t)ri * 128 + (c - 4) * 32;
                else                   s = Ehp + (size_t)sm * 128 + (c - 8) * 32;
            } else                     s = Vh  + (size_t)sm * 128 + c * 32;  // A_NODE c<4
            return valid ? *(const int4*)(s + sh * 8) : make_int4(0,0,0,0);
        }
    };

    auto ldW = [&](const U16* W, int Kw, int c) -> I4x2 {
        const U16* s = W + (size_t)br * Kw + c * 32 + bh * 16;
        I4x2 r;
        r.a = ((const int4*)s)[0];
        r.b = ((const int4*)s)[1];
        return r;
    };

    auto wrA = [&](int b, int4 v) { *(int4*)&As[b][sr][sh * 8] = v; };
    auto wrW = [&](int b, I4x2 w) {
        *(int4*)&Bs[b][br][bh * 16]     = w.a;
        *(int4*)&Bs[b][br][bh * 16 + 8] = w.b;
    };

    auto mfA = [&](int b) {   // A from As[b], W from Bs[b]
        short8 wf[4], af[2];
        #pragma unroll
        for (int g = 0; g < 4; ++g)
            wf[g] = *(const short8*)&Bs[b][wn + g*16 + l16][quad * 8];
        #pragma unroll
        for (int g = 0; g < 2; ++g)
            af[g] = *(const short8*)&As[b][wm + g*16 + l16][quad * 8];
        #pragma unroll
        for (int wg = 0; wg < 4; ++wg)
            #pragma unroll
            for (int ag = 0; ag < 2; ++ag)
                acc[wg][ag] = __builtin_amdgcn_mfma_f32_16x16x32_bf16(
                    wf[wg], af[ag], acc[wg][ag], 0, 0, 0);
    };

    auto mfH = [&](int c, int b) {   // A from Hs slice c, W from Bs[b]
        short8 wf[4], af[2];
        #pragma unroll
        for (int g = 0; g < 4; ++g)
            wf[g] = *(const short8*)&Bs[b][wn + g*16 + l16][quad * 8];
        #pragma unroll
        for (int g = 0; g < 2; ++g)
            af[g] = *(const short8*)&Hs[wm + g*16 + l16][c * 32 + quad * 8];
        #pragma unroll
        for (int wg = 0; wg < 4; ++wg)
            #pragma unroll
            for (int ag = 0; ag < 2; ++ag)
                acc[wg][ag] = __builtin_amdgcn_mfma_f32_16x16x32_bf16(
                    wf[wg], af[ag], acc[wg][ag], 0, 0, 0);
    };

    auto hwrite = [&](const float* bias) {
        #pragma unroll
        for (int wg = 0; wg < 4; ++wg) {
            f32x4 bv = *(const f32x4*)&bias[wn + wg*16 + quad*4];
            #pragma unroll
            for (int ag = 0; ag < 2; ++ag) {
                int m  = wm + ag*16 + l16;
                int n0 = wn + wg*16 + quad*4;
                union { U16 u[4]; uint2 q; } pk;
                #pragma unroll
                for (int rg = 0; rg < 4; ++rg)
                    pk.u[rg] = f2b(fmaxf(acc[wg][ag][rg] + bv[rg], 0.f));
                *(uint2*)&Hs[m][n0] = pk.q;
            }
        }
    };

    int4 ra0, ra1; I4x2 rw0, rw1;
    constexpr int C1 = K1 / 32;

    // ---- phase 1: depth-2 register-prefetch pipeline
    zacc();
    ra0 = ldA(0); rw0 = ldW(W1, K1, 0);
    if (C1 > 1) { ra1 = ldA(1); rw1 = ldW(W1, K1, 1); }
    wrA(0, ra0); wrW(0, rw0);
    wgb();
    #pragma unroll
    for (int c = 0; c < C1; ++c) {
        if (c + 2 < C1) {                      // prefetch chunk c+2 (parity c&1)
            if ((c & 1) == 0) { ra0 = ldA(c + 2); rw0 = ldW(W1, K1, c + 2); }
            else              { ra1 = ldA(c + 2); rw1 = ldW(W1, K1, c + 2); }
        }
        if (c + 1 < C1) {                      // commit chunk c+1 to LDS
            if (((c + 1) & 1) == 0) { wrA(0, ra0); wrW(0, rw0); }
            else                    { wrA(1, ra1); wrW(1, rw1); }
        }
        mfA(c & 1);
        wgb();
    }

    // ---- phase 2 (W-only pipeline; A = Hs)
    rw0 = ldW(W2, 128, 0); rw1 = ldW(W2, 128, 1);
    hwrite(b1);
    wgb();                                     // Hs visible to partner wave
    zacc();
    wrW(0, rw0);
    wgb();
    #pragma unroll
    for (int c = 0; c < 4; ++c) {
        if (c + 2 < 4) {
            if ((c & 1) == 0) rw0 = ldW(W2, 128, c + 2);
            else              rw1 = ldW(W2, 128, c + 2);
        }
        if (c + 1 < 4) {
            if (((c + 1) & 1) == 0) wrW(0, rw0);
            else                    wrW(1, rw1);
        }
        mfH(c, c & 1);
        wgb();
    }

    if (EPI == EPI_DEC) {        // decoder: h2 -> Hs, then dot with w3f
        hwrite(b2);
        wgb();
        int mg = row0 + sr;
        float v = 0.f;
        if (mg < M) {
            const U16* hr = &Hs[sr][sh * 32];
            const float* wr = w3f + sh * 32;
            #pragma unroll
            for (int j = 0; j < 32; ++j) v += b2f(hr[j]) * wr[j];
        }
        v += __shfl_xor(v, 1);
        v += __shfl_xor(v, 2);
        if (sh == 0 && mg < M) outf[mg] = v + b3[0];
        return;
    }

    // ---- phase 3 (W-only pipeline; A = Hs)
    rw0 = ldW(W3, 128, 0); rw1 = ldW(W3, 128, 1);
    hwrite(b2);
    wgb();
    zacc();
    wrW(0, rw0);
    wgb();
    #pragma unroll
    for (int c = 0; c < 4; ++c) {
        if (c + 2 < 4) {
            if ((c & 1) == 0) rw0 = ldW(W3, 128, c + 2);
            else              rw1 = ldW(W3, 128, c + 2);
        }
        if (c + 1 < 4) {
            if (((c + 1) & 1) == 0) wrW(0, rw0);
            else                    wrW(1, rw1);
        }
        mfH(c, c & 1);
        wgb();
    }

    // ---- epilogue (no relu)
    f32x4 bvs[4];
    #pragma unroll
    for (int wg = 0; wg < 4; ++wg)
        bvs[wg] = *(const f32x4*)&b3[wn + wg*16 + quad*4];
    #pragma unroll
    for (int ag = 0; ag < 2; ++ag) {
        int mg = row0 + wm + ag*16 + l16;
        if (mg >= M) continue;
        int sp = 0;
        if (EPI == EPI_EDGE) sp = spos[mg];
        #pragma unroll
        for (int wg = 0; wg < 4; ++wg) {
            int n0 = wn + wg*16 + quad*4;
            f32x4 v;
            #pragma unroll
            for (int rg = 0; rg < 4; ++rg) v[rg] = acc[wg][ag][rg] + bvs[wg][rg];
            size_t o = (size_t)mg * 128 + n0;
            if (EPI == EPI_F) {
                *(f32x4*)&outf[o] = v;
            } else {
                f32x4 c = *(f32x4*)&outf[o];
                c += v;
                *(f32x4*)&outf[o] = c;
                union { U16 u[4]; uint2 q; } pk;
                #pragma unroll
                for (int rg = 0; rg < 4; ++rg) pk.u[rg] = f2b(c[rg]);
                *(uint2*)&outh[o] = pk.q;
                if (EPI == EPI_EDGE)
                    *(f32x4*)&eEs[(size_t)sp * 128 + n0] = v;   // sorted e_emb
            }
        }
    }
}

// in-place LayerNorm over D=128 on fp32 master + bf16 mirror
__global__ __launch_bounds__(256)
void ln_kernel(float* __restrict__ X, const float* __restrict__ g,
               const float* __restrict__ b, U16* __restrict__ Xh, int rows)
{
    int row  = blockIdx.x * 4 + (threadIdx.x >> 6);
    int lane = threadIdx.x & 63;
    if (row >= rows) return;
    float x0 = X[row * DD + lane];
    float x1 = X[row * DD + 64 + lane];
    float s = x0 + x1, q = x0 * x0 + x1 * x1;
    #pragma unroll
    for (int off = 32; off; off >>= 1) {
        s += __shfl_xor(s, off);
        q += __shfl_xor(q, off);
    }
    float mu  = s * (1.f / 128.f);
    float var = q * (1.f / 128.f) - mu * mu;
    float inv = rsqrtf(var + 1e-5f);
    float y0 = (x0 - mu) * inv * g[lane]      + b[lane];
    float y1 = (x1 - mu) * inv * g[64 + lane] + b[64 + lane];
    X[row * DD + lane]       = y0;
    X[row * DD + 64 + lane]  = y1;
    Xh[row * DD + lane]      = f2b(y0);
    Xh[row * DD + 64 + lane] = f2b(y1);
}

extern "C" void kernel_launch(void* const* d_in, const int* in_sizes, int n_in,
                              void* d_out, int out_size, void* d_ws, size_t ws_size,
                              hipStream_t stream)
{
    (void)in_sizes; (void)n_in; (void)out_size; (void)ws_size;

    const float* pos   = (const float*)d_in[0];
    const float* area  = (const float*)d_in[1];
    const float* info  = (const float*)d_in[2];
    const int*   edges = (const int*)d_in[3];
    const float* fv_w1 = (const float*)d_in[4];
    const float* fv_b1 = (const float*)d_in[5];
    const float* fv_w2 = (const float*)d_in[6];
    const float* fv_b2 = (const float*)d_in[7];
    const float* fv_w3 = (const float*)d_in[8];
    const float* fv_b3 = (const float*)d_in[9];
    const float* fv_g  = (const float*)d_in[10];
    const float* fv_bt = (const float*)d_in[11];
    const float* fe_w1 = (const float*)d_in[12];
    const float* fe_b1 = (const float*)d_in[13];
    const float* fe_w2 = (const float*)d_in[14];
    const float* fe_b2 = (const float*)d_in[15];
    const float* fe_w3 = (const float*)d_in[16];
    const float* fe_b3 = (const float*)d_in[17];
    const float* fe_g  = (const float*)d_in[18];
    const float* fe_bt = (const float*)d_in[19];
    const float* ge_w1 = (const float*)d_in[20];
    const float* ge_b1 = (const float*)d_in[21];
    const float* ge_w2 = (const float*)d_in[22];
    const float* ge_b2 = (const float*)d_in[23];
    const float* ge_w3 = (const float*)d_in[24];
    const float* ge_b3 = (const float*)d_in[25];
    const float* gn_w1 = (const float*)d_in[26];
    const float* gn_b1 = (const float*)d_in[27];
    const float* gn_w2 = (const float*)d_in[28];
    const float* gn_b2 = (const float*)d_in[29];
    const float* gn_w3 = (const float*)d_in[30];
    const float* gn_b3 = (const float*)d_in[31];
    const float* de_w1 = (const float*)d_in[32];
    const float* de_b1 = (const float*)d_in[33];
    const float* de_w2 = (const float*)d_in[34];
    const float* de_b2 = (const float*)d_in[35];
    const float* de_w3 = (const float*)d_in[36];
    const float* de_b3 = (const float*)d_in[37];

    // workspace layout (~64 MB)
    char* p = (char*)d_ws;
    float* Vf   = (float*)p;  p += (size_t)N_NODE * 128 * 4;
    float* Ef   = (float*)p;  p += (size_t)N_EDGE * 128 * 4;
    float* eEs  = (float*)p;  p += (size_t)N_EDGE * 128 * 4;
    U16*  Vh    = (U16*)p;    p += (size_t)N_NODE * 128 * 2;
    U16*  Eh    = (U16*)p;    p += (size_t)N_EDGE * 128 * 2;
    U16*  Wt    = (U16*)p;    p += (size_t)WT_TOTAL * 2;
    int*  rowptr = (int*)p;   p += (size_t)(N_NODE + 4) * 4;
    int*  cursor = (int*)p;   p += (size_t)N_NODE * 4;
    int*  cnt    = (int*)p;   p += (size_t)N_NODE * 4;
    int*  spos   = (int*)p;   p += (size_t)N_EDGE * 4;

    const int gbE = (N_EDGE + 63) / 64;   // 625
    const int gbN = (N_NODE + 63) / 64;   // 157

    // ---- prep: weights, CSR
    wprep<<<566, 256, 0, stream>>>(fv_w1, fv_w2, fv_w3, fe_w1, fe_w2, fe_w3,
                                   ge_w1, ge_w2, ge_w3, gn_w1, gn_w2, gn_w3,
                                   de_w1, de_w2, Wt);
    hipMemsetAsync(cnt, 0, (size_t)N_NODE * 4, stream);
    csr_hist<<<(N_EDGE + 255) / 256, 256, 0, stream>>>(edges, cnt, N_EDGE);
    csr_scan<<<1, 256, 0, stream>>>(cnt, rowptr, cursor, N_NODE);
    csr_scatter<<<(N_EDGE + 255) / 256, 256, 0, stream>>>(edges, cursor, spos, N_EDGE);

    // ---- edge encoder (eraw fused) -> Ef; LN -> Ef + Eh
    mlp3<A_ERAW, EPI_F, 32><<<gbE, 256, 0, stream>>>(
        nullptr, Wt + OFF_FE1, fe_b1, Wt + OFF_FE2, fe_b2, Wt + OFF_FE3, fe_b3,
        nullptr, Ef, edges, nullptr, nullptr, nullptr, nullptr, nullptr,
        pos, nullptr, nullptr, nullptr, N_EDGE);
    ln_kernel<<<(N_EDGE + 3) / 4, 256, 0, stream>>>(Ef, fe_g, fe_bt, Eh, N_EDGE);

    // ---- node encoder (encin fused) -> Vf; LN -> Vf + Vh
    mlp3<A_ENCIN, EPI_F, 32><<<gbN, 256, 0, stream>>>(
        nullptr, Wt + OFF_FV1, fv_b1, Wt + OFF_FV2, fv_b2, Wt + OFF_FV3, fv_b3,
        nullptr, Vf, nullptr, nullptr, nullptr, nullptr, nullptr, nullptr,
        pos, area, info, nullptr, N_NODE);
    ln_kernel<<<(N_NODE + 3) / 4, 256, 0, stream>>>(Vf, fv_g, fv_bt, Vh, N_NODE);

    // ---- 15 GNN layers
    for (int l = 0; l < N_LAYER; ++l) {
        mlp3<A_EDGE, EPI_EDGE, 384><<<gbE, 256, 0, stream>>>(
            nullptr,
            Wt + OFF_GE1 + (size_t)l * 49152, ge_b1 + (size_t)l * 128,
            Wt + OFF_GE2 + (size_t)l * 16384, ge_b2 + (size_t)l * 128,
            Wt + OFF_GE3 + (size_t)l * 16384, ge_b3 + (size_t)l * 128,
            Eh, Ef, edges, nullptr, spos, eEs, Vh, Eh,
            nullptr, nullptr, nullptr, nullptr, N_EDGE);
        mlp3<A_NODE, EPI_NODE, 256><<<gbN, 256, 0, stream>>>(
            nullptr,
            Wt + OFF_GN1 + (size_t)l * 32768, gn_b1 + (size_t)l * 128,
            Wt + OFF_GN2 + (size_t)l * 16384, gn_b2 + (size_t)l * 128,
            Wt + OFF_GN3 + (size_t)l * 16384, gn_b3 + (size_t)l * 128,
            Vh, Vf, nullptr, rowptr, nullptr, eEs, Vh, nullptr,
            nullptr, nullptr, nullptr, nullptr, N_NODE);
    }

    // ---- decoder
    mlp3<A_BF16, EPI_DEC, 128><<<gbN, 256, 0, stream>>>(
        Vh, Wt + OFF_DE1, de_b1, Wt + OFF_DE2, de_b2, nullptr, de_b3,
        nullptr, (float*)d_out, nullptr, nullptr, nullptr, nullptr, nullptr, nullptr,
        nullptr, nullptr, nullptr, de_w3, N_NODE);
}